// Round 1
// baseline (722.157 us; speedup 1.0000x reference)
//
#include <hip/hip_runtime.h>
#include <math.h>

#define HH 128
#define WW 128
#define HWSZ (128*128)

typedef __attribute__((ext_vector_type(8))) short short8;
typedef __attribute__((ext_vector_type(4))) float float4v;

__device__ inline short f2bf(float f) {
  unsigned x = __float_as_uint(f);
  unsigned r = (x + 0x7fffu + ((x >> 16) & 1u)) >> 16;
  return (short)r;
}
__device__ inline float bf2f(unsigned short u) {
  return __uint_as_float(((unsigned)u) << 16);
}
// XOR-swizzled short-index of 8-short granule g in LDS row `row` (row stride 32 shorts).
__device__ inline int swz(int row, int g) {
  return row * 32 + ((g ^ ((row >> 1) & 3)) << 3);
}

// ---------------- x: NCHW fp32 -> NHWC bf16 ----
__global__ __launch_bounds__(256) void xcvt_kernel(const float* __restrict__ x,
                                                   short* __restrict__ xbf) {
  __shared__ short tile[32 * 264];
  const int t = threadIdx.x;
  const int h = blockIdx.x, b = blockIdx.y;
  for (int wc = 0; wc < 4; wc++) {
    const int w0 = wc * 32;
    __syncthreads();
    #pragma unroll
    for (int coi = 0; coi < 8; coi++) {
      int ci = coi * 32 + (t >> 3);
      int wq = t & 7;
      float4v f = *(const float4v*)&x[((size_t)b * 256 + ci) * HWSZ + h * WW + w0 + wq * 4];
      tile[(wq * 4 + 0) * 264 + ci] = f2bf(f.x);
      tile[(wq * 4 + 1) * 264 + ci] = f2bf(f.y);
      tile[(wq * 4 + 2) * 264 + ci] = f2bf(f.z);
      tile[(wq * 4 + 3) * 264 + ci] = f2bf(f.w);
    }
    __syncthreads();
    #pragma unroll
    for (int pass = 0; pass < 4; pass++) {
      int wl = pass * 8 + (t >> 5);
      int ci8 = (t & 31) * 8;
      short8 v = *(const short8*)&tile[wl * 264 + ci8];
      *(short8*)&xbf[(((size_t)b * HH + h) * WW + w0 + wl) * 256 + ci8] = v;
    }
  }
}

// ---------------- weight converts (BN scale folded) ----
__global__ void wcvt3_kernel(const float* __restrict__ w, const float* __restrict__ g,
                             const float* __restrict__ v, short* __restrict__ out,
                             int Cin, int CoutW, int co_off) {
  int idx = blockIdx.x * blockDim.x + threadIdx.x;
  int total = CoutW * Cin * 9;
  if (idx >= total) return;
  int t  = idx % 9;
  int ci = (idx / 9) % Cin;
  int co = idx / (9 * Cin);
  float s = g[co] * rsqrtf(v[co] + 1e-5f);
  out[((size_t)t * 256 + co_off + co) * Cin + ci] = f2bf(w[idx] * s);
}

__global__ void wcvt1_kernel(const float* __restrict__ w, const float* __restrict__ g,
                             const float* __restrict__ v, short* __restrict__ out,
                             int Cin, int CoutW) {
  int idx = blockIdx.x * blockDim.x + threadIdx.x;
  if (idx >= CoutW * Cin) return;
  int co = idx / Cin;
  float s = g[co] * rsqrtf(v[co] + 1e-5f);
  out[idx] = f2bf(w[idx] * s);
}

// ---------------- MFMA implicit-GEMM conv3x3 (+optional fused 1x1) ----------------
// 512 thr = 8 waves, 1 block/CU (131.6 KB LDS). Block tile: M = 2 image rows (256 px),
// N = 256 couts. Wave tile 128px x 64co (acc[8][4]). Double-buffered LDS,
// ONE raw s_barrier per 32-ci chunk, counted compiler waits (no vmcnt drain),
// global loads issued a chunk ahead, ds_writes interleaved between dx MFMA clusters.
template<int CIN_A, bool PHASE_B, int SHIFT_MODE, bool SPLIT_OUT, bool OUT_F32>
__global__ __launch_bounds__(512, 2) void conv_mfma(
    const short* __restrict__ srcA, const short* __restrict__ xB,
    const short* __restrict__ wbA, const short* __restrict__ wbB,
    const float* __restrict__ g0, const float* __restrict__ b0,
    const float* __restrict__ m0, const float* __restrict__ v0p,
    const float* __restrict__ g1, const float* __restrict__ b1,
    const float* __restrict__ m1, const float* __restrict__ v1p,
    void* __restrict__ out0, void* __restrict__ out1)
{
  // [buf][plane(2 rows)][130 rows x 32 shorts]  +  [buf][768 rows x 32 shorts]
  __shared__ short A_s[2 * 8320];
  __shared__ short B_s[2 * 24576];

  const int tid  = threadIdx.x;
  const int wave = tid >> 6;
  const int lane = tid & 63;
  const int wm = wave & 1;          // which of the 2 output rows
  const int wn = wave >> 1;         // 0..3 -> 64-co slice
  const int lr = lane & 15;
  const int lk = lane >> 4;

  // XCD-aware chunked swizzle (256 % 8 == 0 -> bijective)
  const int raw = blockIdx.x;
  const int id  = (raw & 7) * 32 + (raw >> 3);
  const int h0  = (id & 63) * 2;    // first of the 2 output rows
  const int b   = id >> 6;

  constexpr int ncA = CIN_A / 32;
  constexpr int chunksA = 3 * ncA;          // always 3 dy; OOB rows zero-filled
  constexpr int total = chunksA + (PHASE_B ? 8 : 0);

  float4v acc[8][4];
  #pragma unroll
  for (int i = 0; i < 8; i++)
    #pragma unroll
    for (int j = 0; j < 4; j++) acc[i][j] = (float4v)(0.0f);

  short8 rA[3], rB[6];
  bool nIsA = true, av0 = false, av1 = false;
  const short* aR = nullptr;
  const short* bB = nullptr;
  int r0 = 0;

  auto decode = [&](int t) {
    nIsA = (t < chunksA);
    if (nIsA) {
      int dy = t / ncA, ci0 = (t % ncA) * 32;
      r0  = h0 + dy - 1;
      av0 = (r0 >= 0);
      av1 = (r0 + 1 <= HH - 1);
      aR = srcA + ((size_t)b * HH) * WW * CIN_A + ci0;
      bB = wbA + (size_t)(dy * 3) * 256 * CIN_A + ci0;
    } else {
      int ci0 = (t - chunksA) * 32;
      aR = xB + (((size_t)b * HH + h0) * WW) * 256 + ci0;
      bB = wbB + ci0;
    }
  };

  auto issueLoads = [&]() {
    if (nIsA) {
      int rr0 = av0 ? r0 : 0;
      int rr1 = av1 ? r0 + 1 : 0;
      { int g = tid; int w = (g >> 2) - 1, q = g & 3;
        rA[0] = (av0 && (unsigned)w < (unsigned)WW)
            ? *(const short8*)(aR + ((size_t)rr0 * WW + w) * CIN_A + q * 8) : (short8)(0); }
      { int g = tid + 512; int pl = (g >= 520) ? 1 : 0; int gg = g - pl * 520;
        int w = (gg >> 2) - 1, q = gg & 3;
        bool vv = pl ? av1 : av0; int rr = pl ? rr1 : rr0;
        rA[1] = (vv && (unsigned)w < (unsigned)WW)
            ? *(const short8*)(aR + ((size_t)rr * WW + w) * CIN_A + q * 8) : (short8)(0); }
      if (tid < 16) { int gg = tid + 504; int w = (gg >> 2) - 1, q = gg & 3;
        rA[2] = (av1 && (unsigned)w < (unsigned)WW)
            ? *(const short8*)(aR + ((size_t)rr1 * WW + w) * CIN_A + q * 8) : (short8)(0); }
      #pragma unroll
      for (int i = 0; i < 6; i++) {
        int idx = tid + i * 512;
        int dx = idx >> 10, rem = idx & 1023, co = rem >> 2, q = rem & 3;
        rB[i] = *(const short8*)(bB + (size_t)(dx * 256 + co) * CIN_A + q * 8);
      }
    } else {
      #pragma unroll
      for (int i = 0; i < 2; i++) {
        int idx = tid + i * 512; int pl = idx >> 9, rem = idx & 511, w = rem >> 2, q = rem & 3;
        rA[i] = *(const short8*)(aR + ((size_t)pl * WW + w) * 256 + q * 8);
      }
      #pragma unroll
      for (int i = 0; i < 2; i++) {
        int idx = tid + i * 512; int co = idx >> 2, q = idx & 3;
        rB[i] = *(const short8*)(bB + (size_t)co * 256 + q * 8);
      }
    }
  };

  int cur = 1;  // prologue writes buf cur^1 = 0

  auto storeP0 = [&]() {
    short* Ab = A_s + (cur ^ 1) * 8320;
    short* Bb = B_s + (cur ^ 1) * 24576;
    if (nIsA) {
      { int g = tid; *(short8*)&Ab[swz(g >> 2, g & 3)] = rA[0]; }
      { int g = tid + 512; int pl = (g >= 520) ? 1 : 0; int gg = g - pl * 520;
        *(short8*)&Ab[pl * 4160 + swz(gg >> 2, gg & 3)] = rA[1]; }
      if (tid < 16) { int gg = tid + 504;
        *(short8*)&Ab[4160 + swz(gg >> 2, gg & 3)] = rA[2]; }
      #pragma unroll
      for (int i = 0; i < 2; i++) {
        int idx = tid + i * 512; int dx = idx >> 10, rem = idx & 1023;
        *(short8*)&Bb[swz(dx * 256 + (rem >> 2), rem & 3)] = rB[i];
      }
    } else {
      #pragma unroll
      for (int i = 0; i < 2; i++) {
        int idx = tid + i * 512; int pl = idx >> 9, rem = idx & 511;
        *(short8*)&Ab[pl * 4160 + swz(rem >> 2, rem & 3)] = rA[i];
      }
      #pragma unroll
      for (int i = 0; i < 2; i++) {
        int idx = tid + i * 512;
        *(short8*)&Bb[swz(idx >> 2, idx & 3)] = rB[i];
      }
    }
  };
  auto storeP1 = [&]() {
    if (!nIsA) return;
    short* Bb = B_s + (cur ^ 1) * 24576;
    #pragma unroll
    for (int i = 2; i < 4; i++) {
      int idx = tid + i * 512; int dx = idx >> 10, rem = idx & 1023;
      *(short8*)&Bb[swz(dx * 256 + (rem >> 2), rem & 3)] = rB[i];
    }
  };
  auto storeP2 = [&]() {
    if (!nIsA) return;
    short* Bb = B_s + (cur ^ 1) * 24576;
    #pragma unroll
    for (int i = 4; i < 6; i++) {
      int idx = tid + i * 512; int dx = idx >> 10, rem = idx & 1023;
      *(short8*)&Bb[swz(dx * 256 + (rem >> 2), rem & 3)] = rB[i];
    }
  };

  auto mfma_dx = [&](int dx) {
    const short* Ab = A_s + cur * 8320 + wm * 4160;
    const short* Bb = B_s + cur * 24576;
    short8 bfv[4];
    #pragma unroll
    for (int ni = 0; ni < 4; ni++)
      bfv[ni] = *(const short8*)&Bb[swz(dx * 256 + wn * 64 + ni * 16 + lr, lk)];
    #pragma unroll
    for (int mi = 0; mi < 8; mi++) {
      short8 afv = *(const short8*)&Ab[swz(mi * 16 + lr + dx, lk)];
      #pragma unroll
      for (int ni = 0; ni < 4; ni++)
        acc[mi][ni] = __builtin_amdgcn_mfma_f32_16x16x32_bf16(afv, bfv[ni], acc[mi][ni], 0, 0, 0);
    }
  };

  // prologue: stage chunk 0 into buf0
  decode(0);
  issueLoads();
  storeP0(); storeP1(); storeP2();
  asm volatile("s_waitcnt lgkmcnt(0)" ::: "memory");
  __builtin_amdgcn_s_barrier();
  __builtin_amdgcn_sched_barrier(0);
  cur = 0;

  #pragma unroll 1
  for (int t = 0; t < total; t++) {
    const bool isA = (t < chunksA);
    const bool hnext = (t + 1 < total);
    if (hnext) { decode(t + 1); issueLoads(); }   // loads in flight across the chunk

    __builtin_amdgcn_s_setprio(1);
    mfma_dx(0);
    __builtin_amdgcn_s_setprio(0);
    if (hnext) storeP0();
    if (isA) {
      __builtin_amdgcn_s_setprio(1);
      mfma_dx(1);
      __builtin_amdgcn_s_setprio(0);
      if (hnext) storeP1();
      __builtin_amdgcn_s_setprio(1);
      mfma_dx(2);
      __builtin_amdgcn_s_setprio(0);
      if (hnext) storeP2();
    } else if (hnext) { storeP1(); storeP2(); }

    // one barrier per chunk; writes done (lgkm), reads done (lgkm); NO vmcnt drain
    asm volatile("s_waitcnt lgkmcnt(0)" ::: "memory");
    __builtin_amdgcn_s_barrier();
    __builtin_amdgcn_sched_barrier(0);
    cur ^= 1;
  }

  // ---------- epilogue: +shift (from raw BN params), relu, store ----------
  const int h2 = h0 + wm;
  #pragma unroll
  for (int ni = 0; ni < 4; ni++) {
    int c = wn * 64 + ni * 16 + lr;           // co 0..255
    float sh;
    if (SHIFT_MODE == 0) {
      float s = g0[c] * rsqrtf(v0p[c] + 1e-5f);
      sh = b0[c] - m0[c] * s;
    } else if (SHIFT_MODE == 1) {
      int cc = c & 127;
      const float* gg = (c < 128) ? g0 : g1;
      const float* bb = (c < 128) ? b0 : b1;
      const float* mm = (c < 128) ? m0 : m1;
      const float* vv = (c < 128) ? v0p : v1p;
      float s = gg[cc] * rsqrtf(vv[cc] + 1e-5f);
      sh = bb[cc] - mm[cc] * s;
    } else {
      float s0 = g0[c] * rsqrtf(v0p[c] + 1e-5f);
      float s1 = g1[c] * rsqrtf(v1p[c] + 1e-5f);
      sh = (b0[c] - m0[c] * s0) + (b1[c] - m1[c] * s1);
    }
    #pragma unroll
    for (int mi = 0; mi < 8; mi++) {
      int w = mi * 16 + lk * 4;
      float4v v = acc[mi][ni];
      v.x = fmaxf(v.x + sh, 0.0f);
      v.y = fmaxf(v.y + sh, 0.0f);
      v.z = fmaxf(v.z + sh, 0.0f);
      v.w = fmaxf(v.w + sh, 0.0f);
      if (OUT_F32) {
        float* ob = (float*)out0;
        *(float4v*)(ob + ((size_t)b * 256 + c) * HWSZ + (size_t)h2 * WW + w) = v;
      } else if (SPLIT_OUT) {
        short* ob = (short*)((c < 128) ? out0 : out1);
        size_t base = (((size_t)b * HH + h2) * WW + w) * 128 + (c & 127);
        ob[base      ] = f2bf(v.x);
        ob[base + 128 ] = f2bf(v.y);
        ob[base + 256 ] = f2bf(v.z);
        ob[base + 384 ] = f2bf(v.w);
      } else {
        short* ob = (short*)out0;
        size_t base = (((size_t)b * HH + h2) * WW + w) * 256 + c;
        ob[base      ] = f2bf(v.x);
        ob[base + 256 ] = f2bf(v.y);
        ob[base + 512 ] = f2bf(v.z);
        ob[base + 768 ] = f2bf(v.w);
      }
    }
  }
}

// ---------------- reverse cummax over H on bf16 NHWC [b][h][w][128], in place
__global__ void colscan_kernel(unsigned* __restrict__ p) {  // uint = 2 bf16
  const int t = threadIdx.x;
  const int wl = t >> 6, cp = t & 63;
  const int w = blockIdx.x * 4 + wl;
  const int b = blockIdx.y;
  float m0 = -INFINITY, m1 = -INFINITY;
  for (int h = HH - 1; h >= 0; h--) {
    size_t idx = (((size_t)b * HH + h) * WW + w) * 64 + cp;
    unsigned u = p[idx];
    float f0 = bf2f((unsigned short)(u & 0xffff));
    float f1 = bf2f((unsigned short)(u >> 16));
    m0 = fmaxf(m0, f0);
    m1 = fmaxf(m1, f1);
    p[idx] = ((unsigned)(unsigned short)f2bf(m1) << 16) | (unsigned short)f2bf(m0);
  }
}

// ---------------- reverse cummax over W on p2 + add p1 -> p1 (bf16 NHWC C=128)
__global__ __launch_bounds__(256) void rowscan_add_kernel(
    const short* __restrict__ p2, short* __restrict__ p1) {
  __shared__ short pl[128 * 128];
  const int tid = threadIdx.x;
  const int hb = blockIdx.x;
  const int b  = blockIdx.y;
  const size_t base = (((size_t)b * HH + hb) * WW) * 128;

  #pragma unroll
  for (int i = 0; i < 8; i++) {
    int idx = tid + i * 256;          // granule of 8 shorts
    *(short8*)&pl[idx * 8] = *(const short8*)(p2 + base + (size_t)idx * 8);
  }
  __syncthreads();
  if (tid < 128) {
    float m = -INFINITY;
    for (int w = WW - 1; w >= 0; w--) {
      int a = w * 128 + tid;
      m = fmaxf(m, bf2f((unsigned short)pl[a]));
      pl[a] = (short)f2bf(m);
    }
  }
  __syncthreads();
  #pragma unroll
  for (int i = 0; i < 8; i++) {
    int idx = tid + i * 256;
    short8 sv = *(const short8*)&pl[idx * 8];
    short8 ov = *(const short8*)(p1 + base + (size_t)idx * 8);
    short8 rv;
    #pragma unroll
    for (int j = 0; j < 8; j++)
      rv[j] = f2bf(bf2f((unsigned short)sv[j]) + bf2f((unsigned short)ov[j]));
    *(short8*)(p1 + base + (size_t)idx * 8) = rv;
  }
}

extern "C" void kernel_launch(void* const* d_in, const int* in_sizes, int n_in,
                              void* d_out, int out_size, void* d_ws, size_t ws_size,
                              hipStream_t stream) {
  const float* x    = (const float*)d_in[0];
  const float* w_p1 = (const float*)d_in[1];
  const float* g_p1 = (const float*)d_in[2];
  const float* b_p1 = (const float*)d_in[3];
  const float* m_p1 = (const float*)d_in[4];
  const float* v_p1 = (const float*)d_in[5];
  const float* w_p2 = (const float*)d_in[6];
  const float* g_p2 = (const float*)d_in[7];
  const float* b_p2 = (const float*)d_in[8];
  const float* m_p2 = (const float*)d_in[9];
  const float* v_p2 = (const float*)d_in[10];
  const float* w_c1 = (const float*)d_in[11];
  const float* g_c1 = (const float*)d_in[12];
  const float* b_c1 = (const float*)d_in[13];
  const float* m_c1 = (const float*)d_in[14];
  const float* v_c1 = (const float*)d_in[15];
  const float* w_c2 = (const float*)d_in[16];
  const float* g_c2 = (const float*)d_in[17];
  const float* b_c2 = (const float*)d_in[18];
  const float* m_c2 = (const float*)d_in[19];
  const float* v_c2 = (const float*)d_in[20];
  const float* w_p3 = (const float*)d_in[21];
  const float* g_p3 = (const float*)d_in[22];
  const float* b_p3 = (const float*)d_in[23];
  const float* m_p3 = (const float*)d_in[24];
  const float* v_p3 = (const float*)d_in[25];

  char* ws = (char*)d_ws;
  // Persistent tensors — total exactly 100,663,296 B.
  short* p1  = (short*)(ws + 0);          // bf16 NHWC [4][128][128][128]  16 MB
  short* p2  = (short*)(ws + 16777216);   // bf16 NHWC [4][128][128][128]  16 MB
  short* r   = (short*)(ws + 33554432);   // bf16 NHWC [4][128][128][256]  32 MB
  short* xbf = (short*)(ws + 67108864);   // bf16 NHWC [4][128][128][256]  32 MB
  // Weight buffers overlay dead regions (stream-ordered):
  short* wb12 = r;                        // [9][256][256]; dead before c1 writes r
  short* wbc1 = p2;                       // [9][256][128]; written after rowscan_add
  short* wbc2 = (short*)(ws + 16777216 + 589824);  // [256][256], in p2 region
  short* wbp3 = p1;                       // [9][256][256]; written after c1

  // x -> NHWC bf16
  xcvt_kernel<<<dim3(128, 4), 256, 0, stream>>>(x, xbf);

  // weights for p1|p2 (into r region)
  wcvt3_kernel<<<(128 * 256 * 9 + 255) / 256, 256, 0, stream>>>(w_p1, g_p1, v_p1, wb12, 256, 128, 0);
  wcvt3_kernel<<<(128 * 256 * 9 + 255) / 256, 256, 0, stream>>>(w_p2, g_p2, v_p2, wb12, 256, 128, 128);

  // p1|p2 = relu(bn(conv3x3(x)))
  conv_mfma<256, false, 1, true, false><<<dim3(256), 512, 0, stream>>>(
      xbf, nullptr, wb12, nullptr,
      g_p1, b_p1, m_p1, v_p1, g_p2, b_p2, m_p2, v_p2, (void*)p1, (void*)p2);

  // corner pooling: cp1 in-place on p1, then s = rowscan(p2) + cp1 -> p1
  colscan_kernel<<<dim3(32, 4), 256, 0, stream>>>((unsigned*)p1);
  rowscan_add_kernel<<<dim3(128, 4), 256, 0, stream>>>(p2, p1);

  // weights for c1 (3x3) and c2 (1x1) into p2 region (p2 dead now)
  wcvt3_kernel<<<(256 * 128 * 9 + 255) / 256, 256, 0, stream>>>(w_c1, g_c1, v_c1, wbc1, 128, 256, 0);
  wcvt1_kernel<<<(256 * 256 + 255) / 256, 256, 0, stream>>>(w_c2, g_c2, v_c2, wbc2, 256, 256);

  // r = relu(bn1(conv3x3(s)) + bn2(conv1x1(x)))
  conv_mfma<128, true, 2, false, false><<<dim3(256), 512, 0, stream>>>(
      p1, xbf, wbc1, wbc2,
      g_c1, b_c1, m_c1, v_c1, g_c2, b_c2, m_c2, v_c2, (void*)r, nullptr);

  // weights for p3 into p1 region (p1 dead now)
  wcvt3_kernel<<<(256 * 256 * 9 + 255) / 256, 256, 0, stream>>>(w_p3, g_p3, v_p3, wbp3, 256, 256, 0);

  // out = relu(bn(conv3x3(r)))  — fp32 NCHW float4 stores
  conv_mfma<256, false, 0, false, true><<<dim3(256), 512, 0, stream>>>(
      r, nullptr, wbp3, nullptr,
      g_p3, b_p3, m_p3, v_p3, nullptr, nullptr, nullptr, nullptr, d_out, nullptr);
}

// Round 2
// 563.650 us; speedup vs baseline: 1.2812x; 1.2812x over previous
//
#include <hip/hip_runtime.h>
#include <math.h>

#define HH 128
#define WW 128
#define HWSZ (128*128)

typedef __attribute__((ext_vector_type(8))) short short8;
typedef __attribute__((ext_vector_type(4))) float float4v;

__device__ inline short f2bf(float f) {
  unsigned x = __float_as_uint(f);
  unsigned r = (x + 0x7fffu + ((x >> 16) & 1u)) >> 16;
  return (short)r;
}
__device__ inline float bf2f(unsigned short u) {
  return __uint_as_float(((unsigned)u) << 16);
}
// XOR-swizzled short-index of 8-short granule g in LDS row `row` (row stride 32 shorts).
__device__ inline int swz(int row, int g) {
  return row * 32 + ((g ^ ((row >> 1) & 3)) << 3);
}

// global->LDS direct DMA, 16B per lane, linear LDS dest (wave-uniform base + lane*16)
__device__ inline void gload_lds16(const short* g, short* l) {
  __builtin_amdgcn_global_load_lds(
      (const __attribute__((address_space(1))) void*)g,
      (__attribute__((address_space(3))) void*)l, 16, 0, 0);
}

// ---------------- x: NCHW fp32 -> NHWC bf16 ----
__global__ __launch_bounds__(256) void xcvt_kernel(const float* __restrict__ x,
                                                   short* __restrict__ xbf) {
  __shared__ short tile[32 * 264];
  const int t = threadIdx.x;
  const int h = blockIdx.x, b = blockIdx.y;
  for (int wc = 0; wc < 4; wc++) {
    const int w0 = wc * 32;
    __syncthreads();
    #pragma unroll
    for (int coi = 0; coi < 8; coi++) {
      int ci = coi * 32 + (t >> 3);
      int wq = t & 7;
      float4v f = *(const float4v*)&x[((size_t)b * 256 + ci) * HWSZ + h * WW + w0 + wq * 4];
      tile[(wq * 4 + 0) * 264 + ci] = f2bf(f.x);
      tile[(wq * 4 + 1) * 264 + ci] = f2bf(f.y);
      tile[(wq * 4 + 2) * 264 + ci] = f2bf(f.z);
      tile[(wq * 4 + 3) * 264 + ci] = f2bf(f.w);
    }
    __syncthreads();
    #pragma unroll
    for (int pass = 0; pass < 4; pass++) {
      int wl = pass * 8 + (t >> 5);
      int ci8 = (t & 31) * 8;
      short8 v = *(const short8*)&tile[wl * 264 + ci8];
      *(short8*)&xbf[(((size_t)b * HH + h) * WW + w0 + wl) * 256 + ci8] = v;
    }
  }
}

// ---------------- weight converts (BN scale folded), PRE-SWIZZLED chunk-linear layout ----
// 3x3: out granule layout [dy][ci_chunk][dx][co(256)][g'] with g' = g ^ ((row>>1)&3),
// row = dx*256+co. conv stages each 48KB chunk with linear global_load_lds; swz() reads
// then see natural (row, g).
__global__ void wcvt3_kernel(const float* __restrict__ w, const float* __restrict__ g,
                             const float* __restrict__ v, short* __restrict__ out,
                             int Cin, int CoutW, int co_off) {
  int idx = blockIdx.x * blockDim.x + threadIdx.x;
  int total = CoutW * Cin * 9;
  if (idx >= total) return;
  int t  = idx % 9;
  int ci = (idx / 9) % Cin;
  int co = idx / (9 * Cin);
  int dy = t / 3, dx = t % 3;
  float s = g[co] * rsqrtf(v[co] + 1e-5f);
  int cog = co_off + co;
  int chunk = ci >> 5;
  int gq = (ci >> 3) & 3;
  int row = dx * 256 + cog;
  int gp = gq ^ ((row >> 1) & 3);
  size_t o = ((((size_t)(dy * (Cin >> 5) + chunk) * 3 + dx) * 256 + cog) * 4 + gp) * 8 + (ci & 7);
  out[o] = f2bf(w[idx] * s);
}

// 1x1: [ci_chunk][co(256)][g'] with g' = g ^ ((co>>1)&3)
__global__ void wcvt1_kernel(const float* __restrict__ w, const float* __restrict__ g,
                             const float* __restrict__ v, short* __restrict__ out,
                             int Cin, int CoutW) {
  int idx = blockIdx.x * blockDim.x + threadIdx.x;
  if (idx >= CoutW * Cin) return;
  int co = idx / Cin;
  int ci = idx % Cin;
  float s = g[co] * rsqrtf(v[co] + 1e-5f);
  int chunk = ci >> 5;
  int gq = (ci >> 3) & 3;
  int gp = gq ^ ((co >> 1) & 3);
  size_t o = (((size_t)chunk * 256 + co) * 4 + gp) * 8 + (ci & 7);
  out[o] = f2bf(w[idx] * s);
}

// ---------------- MFMA implicit-GEMM conv3x3 (+optional fused 1x1) ----------------
// 512 thr = 8 waves, 1 block/CU (131.6 KB LDS). Block tile: M = 2 image rows (256 px),
// N = 256 couts. Wave tile 128px x 64co (acc[8][4] -> AGPRs). Double-buffered LDS,
// ONE s_barrier per 32-ci chunk. B (weights) staged via global_load_lds from
// pre-swizzled linear layout (zero staging VGPRs); A register-staged (12 VGPRs).
template<int CIN_A, bool PHASE_B, int SHIFT_MODE, bool SPLIT_OUT, bool OUT_F32>
__global__ __launch_bounds__(512, 2) void conv_mfma(
    const short* __restrict__ srcA, const short* __restrict__ xB,
    const short* __restrict__ wbA, const short* __restrict__ wbB,
    const float* __restrict__ g0, const float* __restrict__ b0,
    const float* __restrict__ m0, const float* __restrict__ v0p,
    const float* __restrict__ g1, const float* __restrict__ b1,
    const float* __restrict__ m1, const float* __restrict__ v1p,
    void* __restrict__ out0, void* __restrict__ out1)
{
  // [buf][plane(2 rows)][130 rows x 32 shorts]  +  [buf][768 rows x 32 shorts]
  __shared__ short A_s[2 * 8320];
  __shared__ short B_s[2 * 24576];

  const int tid  = threadIdx.x;
  const int wave = tid >> 6;
  const int lane = tid & 63;
  const int wm = wave & 1;          // which of the 2 output rows
  const int wn = wave >> 1;         // 0..3 -> 64-co slice
  const int lr = lane & 15;
  const int lk = lane >> 4;

  // XCD-aware chunked swizzle (256 % 8 == 0 -> bijective)
  const int raw = blockIdx.x;
  const int id  = (raw & 7) * 32 + (raw >> 3);
  const int h0  = (id & 63) * 2;    // first of the 2 output rows
  const int b   = id >> 6;

  constexpr int ncA = CIN_A / 32;
  constexpr int chunksA = 3 * ncA;          // always 3 dy; OOB rows zero-filled
  constexpr int total = chunksA + (PHASE_B ? 8 : 0);

  float4v acc[8][4];
  #pragma unroll
  for (int i = 0; i < 8; i++)
    #pragma unroll
    for (int j = 0; j < 4; j++) acc[i][j] = (float4v)(0.0f);

  short8 rA[3];
  bool nIsA = true, av0 = false, av1 = false;
  const short* aR = nullptr;
  const short* bB = nullptr;
  int r0 = 0;

  auto decode = [&](int t) {
    nIsA = (t < chunksA);
    if (nIsA) {
      int dy = t / ncA, c = t % ncA;
      r0  = h0 + dy - 1;
      av0 = (r0 >= 0);
      av1 = (r0 + 1 <= HH - 1);
      aR = srcA + ((size_t)b * HH) * WW * CIN_A + c * 32;
      bB = wbA + (size_t)(dy * ncA + c) * 24576;   // 3*256*32 shorts per chunk
    } else {
      int tb = t - chunksA;
      aR = xB + (((size_t)b * HH + h0) * WW) * 256 + tb * 32;
      bB = wbB + (size_t)tb * 8192;                // 256*32 shorts per chunk
    }
  };

  auto issueA = [&]() {
    if (nIsA) {
      int rr0 = av0 ? r0 : 0;
      int rr1 = av1 ? r0 + 1 : 0;
      { int g = tid; int w = (g >> 2) - 1, q = g & 3;
        rA[0] = (av0 && (unsigned)w < (unsigned)WW)
            ? *(const short8*)(aR + ((size_t)rr0 * WW + w) * CIN_A + q * 8) : (short8)(0); }
      { int g = tid + 512; int pl = (g >= 520) ? 1 : 0; int gg = g - pl * 520;
        int w = (gg >> 2) - 1, q = gg & 3;
        bool vv = pl ? av1 : av0; int rr = pl ? rr1 : rr0;
        rA[1] = (vv && (unsigned)w < (unsigned)WW)
            ? *(const short8*)(aR + ((size_t)rr * WW + w) * CIN_A + q * 8) : (short8)(0); }
      if (tid < 16) { int gg = tid + 504; int w = (gg >> 2) - 1, q = gg & 3;
        rA[2] = (av1 && (unsigned)w < (unsigned)WW)
            ? *(const short8*)(aR + ((size_t)rr1 * WW + w) * CIN_A + q * 8) : (short8)(0); }
    } else {
      #pragma unroll
      for (int i = 0; i < 2; i++) {
        int idx = tid + i * 512; int pl = idx >> 9, rem = idx & 511, w = rem >> 2, q = rem & 3;
        rA[i] = *(const short8*)(aR + ((size_t)pl * WW + w) * 256 + q * 8);
      }
    }
  };

  // B: linear global_load_lds from pre-swizzled weights (issued AFTER issueA so the
  // A-store's compiler vmcnt wait does not drain these)
  auto issueB = [&](int buf) {
    short* Bb = B_s + buf * 24576;
    if (nIsA) {
      #pragma unroll
      for (int i = 0; i < 6; i++)
        gload_lds16(bB + ((size_t)i * 512 + tid) * 8, Bb + (i * 512 + wave * 64) * 8);
    } else {
      #pragma unroll
      for (int i = 0; i < 2; i++)
        gload_lds16(bB + ((size_t)i * 512 + tid) * 8, Bb + (i * 512 + wave * 64) * 8);
    }
  };

  auto storeA = [&](int buf) {
    short* Ab = A_s + buf * 8320;
    if (nIsA) {
      { int g = tid; *(short8*)&Ab[swz(g >> 2, g & 3)] = rA[0]; }
      { int g = tid + 512; int pl = (g >= 520) ? 1 : 0; int gg = g - pl * 520;
        *(short8*)&Ab[pl * 4160 + swz(gg >> 2, gg & 3)] = rA[1]; }
      if (tid < 16) { int gg = tid + 504;
        *(short8*)&Ab[4160 + swz(gg >> 2, gg & 3)] = rA[2]; }
    } else {
      #pragma unroll
      for (int i = 0; i < 2; i++) {
        int idx = tid + i * 512; int pl = idx >> 9, rem = idx & 511;
        *(short8*)&Ab[pl * 4160 + swz(rem >> 2, rem & 3)] = rA[i];
      }
    }
  };

  int cur = 0;

  auto mfma_dx = [&](int dx) {
    const short* Ab = A_s + cur * 8320 + wm * 4160;
    const short* Bb = B_s + cur * 24576;
    short8 bfv[4];
    #pragma unroll
    for (int ni = 0; ni < 4; ni++)
      bfv[ni] = *(const short8*)&Bb[swz(dx * 256 + wn * 64 + ni * 16 + lr, lk)];
    #pragma unroll
    for (int mi = 0; mi < 8; mi++) {
      short8 afv = *(const short8*)&Ab[swz(mi * 16 + lr + dx, lk)];
      #pragma unroll
      for (int ni = 0; ni < 4; ni++)
        acc[mi][ni] = __builtin_amdgcn_mfma_f32_16x16x32_bf16(afv, bfv[ni], acc[mi][ni], 0, 0, 0);
    }
  };

  // prologue: stage chunk 0 into buf0
  decode(0);
  issueA();
  issueB(0);
  storeA(0);
  asm volatile("s_waitcnt vmcnt(0) lgkmcnt(0)" ::: "memory");
  __builtin_amdgcn_s_barrier();
  __builtin_amdgcn_sched_barrier(0);

  #pragma unroll 1
  for (int t = 0; t < total; t++) {
    const bool isA = (t < chunksA);
    const bool hnext = (t + 1 < total);
    if (hnext) { decode(t + 1); issueA(); issueB(cur ^ 1); }  // loads in flight across chunk

    __builtin_amdgcn_s_setprio(1);
    mfma_dx(0);
    __builtin_amdgcn_s_setprio(0);
    if (hnext) storeA(cur ^ 1);
    if (isA) {
      __builtin_amdgcn_s_setprio(1);
      mfma_dx(1);
      mfma_dx(2);
      __builtin_amdgcn_s_setprio(0);
    }

    // one barrier per chunk; B-DMA for next buf was issued a full chunk ago
    asm volatile("s_waitcnt vmcnt(0) lgkmcnt(0)" ::: "memory");
    __builtin_amdgcn_s_barrier();
    __builtin_amdgcn_sched_barrier(0);
    cur ^= 1;
  }

  // ---------- epilogue: +shift (from raw BN params), relu, store ----------
  const int h2 = h0 + wm;
  #pragma unroll
  for (int ni = 0; ni < 4; ni++) {
    int c = wn * 64 + ni * 16 + lr;           // co 0..255
    float sh;
    if (SHIFT_MODE == 0) {
      float s = g0[c] * rsqrtf(v0p[c] + 1e-5f);
      sh = b0[c] - m0[c] * s;
    } else if (SHIFT_MODE == 1) {
      int cc = c & 127;
      const float* gg = (c < 128) ? g0 : g1;
      const float* bb = (c < 128) ? b0 : b1;
      const float* mm = (c < 128) ? m0 : m1;
      const float* vv = (c < 128) ? v0p : v1p;
      float s = gg[cc] * rsqrtf(vv[cc] + 1e-5f);
      sh = bb[cc] - mm[cc] * s;
    } else {
      float s0 = g0[c] * rsqrtf(v0p[c] + 1e-5f);
      float s1 = g1[c] * rsqrtf(v1p[c] + 1e-5f);
      sh = (b0[c] - m0[c] * s0) + (b1[c] - m1[c] * s1);
    }
    #pragma unroll
    for (int mi = 0; mi < 8; mi++) {
      int w = mi * 16 + lk * 4;
      float4v v = acc[mi][ni];
      v.x = fmaxf(v.x + sh, 0.0f);
      v.y = fmaxf(v.y + sh, 0.0f);
      v.z = fmaxf(v.z + sh, 0.0f);
      v.w = fmaxf(v.w + sh, 0.0f);
      if (OUT_F32) {
        float* ob = (float*)out0;
        *(float4v*)(ob + ((size_t)b * 256 + c) * HWSZ + (size_t)h2 * WW + w) = v;
      } else if (SPLIT_OUT) {
        short* ob = (short*)((c < 128) ? out0 : out1);
        size_t base = (((size_t)b * HH + h2) * WW + w) * 128 + (c & 127);
        ob[base      ] = f2bf(v.x);
        ob[base + 128 ] = f2bf(v.y);
        ob[base + 256 ] = f2bf(v.z);
        ob[base + 384 ] = f2bf(v.w);
      } else {
        short* ob = (short*)out0;
        size_t base = (((size_t)b * HH + h2) * WW + w) * 256 + c;
        ob[base      ] = f2bf(v.x);
        ob[base + 256 ] = f2bf(v.y);
        ob[base + 512 ] = f2bf(v.z);
        ob[base + 768 ] = f2bf(v.w);
      }
    }
  }
}

// ---------------- reverse cummax over H on bf16 NHWC [b][h][w][128], in place
__global__ void colscan_kernel(unsigned* __restrict__ p) {  // uint = 2 bf16
  const int t = threadIdx.x;
  const int wl = t >> 6, cp = t & 63;
  const int w = blockIdx.x * 4 + wl;
  const int b = blockIdx.y;
  float m0 = -INFINITY, m1 = -INFINITY;
  for (int h = HH - 1; h >= 0; h--) {
    size_t idx = (((size_t)b * HH + h) * WW + w) * 64 + cp;
    unsigned u = p[idx];
    float f0 = bf2f((unsigned short)(u & 0xffff));
    float f1 = bf2f((unsigned short)(u >> 16));
    m0 = fmaxf(m0, f0);
    m1 = fmaxf(m1, f1);
    p[idx] = ((unsigned)(unsigned short)f2bf(m1) << 16) | (unsigned short)f2bf(m0);
  }
}

// ---------------- reverse cummax over W on p2 + add p1 -> p1 (bf16 NHWC C=128)
__global__ __launch_bounds__(256) void rowscan_add_kernel(
    const short* __restrict__ p2, short* __restrict__ p1) {
  __shared__ short pl[128 * 128];
  const int tid = threadIdx.x;
  const int hb = blockIdx.x;
  const int b  = blockIdx.y;
  const size_t base = (((size_t)b * HH + hb) * WW) * 128;

  #pragma unroll
  for (int i = 0; i < 8; i++) {
    int idx = tid + i * 256;          // granule of 8 shorts
    *(short8*)&pl[idx * 8] = *(const short8*)(p2 + base + (size_t)idx * 8);
  }
  __syncthreads();
  if (tid < 128) {
    float m = -INFINITY;
    for (int w = WW - 1; w >= 0; w--) {
      int a = w * 128 + tid;
      m = fmaxf(m, bf2f((unsigned short)pl[a]));
      pl[a] = (short)f2bf(m);
    }
  }
  __syncthreads();
  #pragma unroll
  for (int i = 0; i < 8; i++) {
    int idx = tid + i * 256;
    short8 sv = *(const short8*)&pl[idx * 8];
    short8 ov = *(const short8*)(p1 + base + (size_t)idx * 8);
    short8 rv;
    #pragma unroll
    for (int j = 0; j < 8; j++)
      rv[j] = f2bf(bf2f((unsigned short)sv[j]) + bf2f((unsigned short)ov[j]));
    *(short8*)(p1 + base + (size_t)idx * 8) = rv;
  }
}

extern "C" void kernel_launch(void* const* d_in, const int* in_sizes, int n_in,
                              void* d_out, int out_size, void* d_ws, size_t ws_size,
                              hipStream_t stream) {
  const float* x    = (const float*)d_in[0];
  const float* w_p1 = (const float*)d_in[1];
  const float* g_p1 = (const float*)d_in[2];
  const float* b_p1 = (const float*)d_in[3];
  const float* m_p1 = (const float*)d_in[4];
  const float* v_p1 = (const float*)d_in[5];
  const float* w_p2 = (const float*)d_in[6];
  const float* g_p2 = (const float*)d_in[7];
  const float* b_p2 = (const float*)d_in[8];
  const float* m_p2 = (const float*)d_in[9];
  const float* v_p2 = (const float*)d_in[10];
  const float* w_c1 = (const float*)d_in[11];
  const float* g_c1 = (const float*)d_in[12];
  const float* b_c1 = (const float*)d_in[13];
  const float* m_c1 = (const float*)d_in[14];
  const float* v_c1 = (const float*)d_in[15];
  const float* w_c2 = (const float*)d_in[16];
  const float* g_c2 = (const float*)d_in[17];
  const float* b_c2 = (const float*)d_in[18];
  const float* m_c2 = (const float*)d_in[19];
  const float* v_c2 = (const float*)d_in[20];
  const float* w_p3 = (const float*)d_in[21];
  const float* g_p3 = (const float*)d_in[22];
  const float* b_p3 = (const float*)d_in[23];
  const float* m_p3 = (const float*)d_in[24];
  const float* v_p3 = (const float*)d_in[25];

  char* ws = (char*)d_ws;
  // Persistent tensors — total exactly 100,663,296 B.
  short* p1  = (short*)(ws + 0);          // bf16 NHWC [4][128][128][128]  16 MB
  short* p2  = (short*)(ws + 16777216);   // bf16 NHWC [4][128][128][128]  16 MB
  short* r   = (short*)(ws + 33554432);   // bf16 NHWC [4][128][128][256]  32 MB
  short* xbf = (short*)(ws + 67108864);   // bf16 NHWC [4][128][128][256]  32 MB
  // Weight buffers overlay dead regions (stream-ordered):
  short* wb12 = r;                        // [9][256][256]; dead before c1 writes r
  short* wbc1 = p2;                       // [9][256][128]; written after rowscan_add
  short* wbc2 = (short*)(ws + 16777216 + 589824);  // [256][256], in p2 region
  short* wbp3 = p1;                       // [9][256][256]; written after c1

  // x -> NHWC bf16
  xcvt_kernel<<<dim3(128, 4), 256, 0, stream>>>(x, xbf);

  // weights for p1|p2 (into r region)
  wcvt3_kernel<<<(128 * 256 * 9 + 255) / 256, 256, 0, stream>>>(w_p1, g_p1, v_p1, wb12, 256, 128, 0);
  wcvt3_kernel<<<(128 * 256 * 9 + 255) / 256, 256, 0, stream>>>(w_p2, g_p2, v_p2, wb12, 256, 128, 128);

  // p1|p2 = relu(bn(conv3x3(x)))
  conv_mfma<256, false, 1, true, false><<<dim3(256), 512, 0, stream>>>(
      xbf, nullptr, wb12, nullptr,
      g_p1, b_p1, m_p1, v_p1, g_p2, b_p2, m_p2, v_p2, (void*)p1, (void*)p2);

  // corner pooling: cp1 in-place on p1, then s = rowscan(p2) + cp1 -> p1
  colscan_kernel<<<dim3(32, 4), 256, 0, stream>>>((unsigned*)p1);
  rowscan_add_kernel<<<dim3(128, 4), 256, 0, stream>>>(p2, p1);

  // weights for c1 (3x3) and c2 (1x1) into p2 region (p2 dead now)
  wcvt3_kernel<<<(256 * 128 * 9 + 255) / 256, 256, 0, stream>>>(w_c1, g_c1, v_c1, wbc1, 128, 256, 0);
  wcvt1_kernel<<<(256 * 256 + 255) / 256, 256, 0, stream>>>(w_c2, g_c2, v_c2, wbc2, 256, 256);

  // r = relu(bn1(conv3x3(s)) + bn2(conv1x1(x)))
  conv_mfma<128, true, 2, false, false><<<dim3(256), 512, 0, stream>>>(
      p1, xbf, wbc1, wbc2,
      g_c1, b_c1, m_c1, v_c1, g_c2, b_c2, m_c2, v_c2, (void*)r, nullptr);

  // weights for p3 into p1 region (p1 dead now)
  wcvt3_kernel<<<(256 * 256 * 9 + 255) / 256, 256, 0, stream>>>(w_p3, g_p3, v_p3, wbp3, 256, 256, 0);

  // out = relu(bn(conv3x3(r)))  — fp32 NCHW float4 stores
  conv_mfma<256, false, 0, false, true><<<dim3(256), 512, 0, stream>>>(
      r, nullptr, wbp3, nullptr,
      g_p3, b_p3, m_p3, v_p3, nullptr, nullptr, nullptr, nullptr, d_out, nullptr);
}

// Round 3
// 549.942 us; speedup vs baseline: 1.3132x; 1.0249x over previous
//
#include <hip/hip_runtime.h>
#include <math.h>

#define HH 128
#define WW 128
#define HWSZ (128*128)

typedef __attribute__((ext_vector_type(8))) short short8;
typedef __attribute__((ext_vector_type(4))) float float4v;

__device__ inline short f2bf(float f) {
  unsigned x = __float_as_uint(f);
  unsigned r = (x + 0x7fffu + ((x >> 16) & 1u)) >> 16;
  return (short)r;
}
__device__ inline float bf2f(unsigned short u) {
  return __uint_as_float(((unsigned)u) << 16);
}
// XOR-swizzled short-index of 8-short granule g in LDS row `row` (row stride 32 shorts).
__device__ inline int swz(int row, int g) {
  return row * 32 + ((g ^ ((row >> 1) & 3)) << 3);
}
// A-tensor global pre-swizzle pattern for column w (LDS row = w+1)
__device__ inline int apat(int w) { return ((w + 1) >> 1) & 3; }

// global->LDS direct DMA, 16B per lane: LDS dest = wave-uniform base + lane*16
__device__ inline void gload_lds16(const short* g, short* l) {
  __builtin_amdgcn_global_load_lds(
      (const __attribute__((address_space(1))) void*)g,
      (__attribute__((address_space(3))) void*)l, 16, 0, 0);
}

// ---------------- x: NCHW fp32 -> NHWC bf16, ci-granules pre-swizzled by apat(w) ----
__global__ __launch_bounds__(256) void xcvt_kernel(const float* __restrict__ x,
                                                   short* __restrict__ xbf) {
  __shared__ short tile[32 * 264];
  const int t = threadIdx.x;
  const int h = blockIdx.x, b = blockIdx.y;
  for (int wc = 0; wc < 4; wc++) {
    const int w0 = wc * 32;
    __syncthreads();
    #pragma unroll
    for (int coi = 0; coi < 8; coi++) {
      int ci = coi * 32 + (t >> 3);
      int wq = t & 7;
      float4v f = *(const float4v*)&x[((size_t)b * 256 + ci) * HWSZ + h * WW + w0 + wq * 4];
      tile[(wq * 4 + 0) * 264 + ci] = f2bf(f.x);
      tile[(wq * 4 + 1) * 264 + ci] = f2bf(f.y);
      tile[(wq * 4 + 2) * 264 + ci] = f2bf(f.z);
      tile[(wq * 4 + 3) * 264 + ci] = f2bf(f.w);
    }
    __syncthreads();
    #pragma unroll
    for (int pass = 0; pass < 4; pass++) {
      int wl = pass * 8 + (t >> 5);
      int g  = t & 31;
      int gp = g ^ apat(w0 + wl);           // swizzle low 2 bits (q within 32-ci chunk)
      short8 v = *(const short8*)&tile[wl * 264 + g * 8];
      *(short8*)&xbf[(((size_t)b * HH + h) * WW + w0 + wl) * 256 + gp * 8] = v;
    }
  }
}

// ---------------- weight converts (BN scale folded), PRE-SWIZZLED chunk-linear layout ----
__global__ void wcvt3_kernel(const float* __restrict__ w, const float* __restrict__ g,
                             const float* __restrict__ v, short* __restrict__ out,
                             int Cin, int CoutW, int co_off) {
  int idx = blockIdx.x * blockDim.x + threadIdx.x;
  int total = CoutW * Cin * 9;
  if (idx >= total) return;
  int t  = idx % 9;
  int ci = (idx / 9) % Cin;
  int co = idx / (9 * Cin);
  int dy = t / 3, dx = t % 3;
  float s = g[co] * rsqrtf(v[co] + 1e-5f);
  int cog = co_off + co;
  int chunk = ci >> 5;
  int gq = (ci >> 3) & 3;
  int row = dx * 256 + cog;
  int gp = gq ^ ((row >> 1) & 3);
  size_t o = ((((size_t)(dy * (Cin >> 5) + chunk) * 3 + dx) * 256 + cog) * 4 + gp) * 8 + (ci & 7);
  out[o] = f2bf(w[idx] * s);
}

__global__ void wcvt1_kernel(const float* __restrict__ w, const float* __restrict__ g,
                             const float* __restrict__ v, short* __restrict__ out,
                             int Cin, int CoutW) {
  int idx = blockIdx.x * blockDim.x + threadIdx.x;
  if (idx >= CoutW * Cin) return;
  int co = idx / Cin;
  int ci = idx % Cin;
  float s = g[co] * rsqrtf(v[co] + 1e-5f);
  int chunk = ci >> 5;
  int gq = (ci >> 3) & 3;
  int gp = gq ^ ((co >> 1) & 3);
  size_t o = (((size_t)chunk * 256 + co) * 4 + gp) * 8 + (ci & 7);
  out[o] = f2bf(w[idx] * s);
}

// ---------------- MFMA implicit-GEMM conv3x3 (+optional fused 1x1) ----------------
// 512 thr = 8 waves, 1 block/CU (131.6 KB LDS). Block tile: M = 2 image rows (256 px),
// N = 256 couts. Wave tile 128px x 64co (acc[8][4] -> AGPRs). Double-buffered LDS.
// ALL staging via global_load_lds from pre-swizzled global layouts: zero staging VGPRs,
// zero staging ds_writes. One s_barrier per 32-ci chunk; DMAs issued a full MFMA
// phase (~3.7k cyc) before the vmcnt drain.
template<int CIN_A, bool PHASE_B, int SHIFT_MODE, bool SPLIT_OUT, bool OUT_F32>
__global__ __launch_bounds__(512, 2) void conv_mfma(
    const short* __restrict__ srcA, const short* __restrict__ xB,
    const short* __restrict__ wbA, const short* __restrict__ wbB,
    const float* __restrict__ g0, const float* __restrict__ b0,
    const float* __restrict__ m0, const float* __restrict__ v0p,
    const float* __restrict__ g1, const float* __restrict__ b1,
    const float* __restrict__ m1, const float* __restrict__ v1p,
    void* __restrict__ out0, void* __restrict__ out1)
{
  // [buf][plane(input row)][130 w-rows x 32 shorts]; rows 0 and 129 = halo (pre-zeroed)
  __shared__ short A_s[2 * 8320];
  __shared__ short B_s[2 * 24576];

  const int tid  = threadIdx.x;
  const int wave = tid >> 6;
  const int lane = tid & 63;
  const int wm = wave & 1;          // which of the 2 output rows
  const int wn = wave >> 1;         // 0..3 -> 64-co slice
  const int lr = lane & 15;
  const int lk = lane >> 4;

  // A-DMA geometry: waves 0-3 -> plane 0, waves 4-7 -> plane 1; 2 granule-blocks each
  const int plA = wave >> 2;
  const int wA  = ((wave & 3) << 4) + (lane >> 2);   // w column 0..63 (second block +64)
  const int qA  = lane & 3;

  // XCD-aware chunked swizzle (256 % 8 == 0 -> bijective)
  const int raw = blockIdx.x;
  const int id  = (raw & 7) * 32 + (raw >> 3);
  const int h0  = (id & 63) * 2;    // first of the 2 output rows
  const int b   = id >> 6;

  constexpr int ncA = CIN_A / 32;
  constexpr int chunksA = 3 * ncA;          // always 3 dy; OOB planes zero-filled
  constexpr int total = chunksA + (PHASE_B ? 8 : 0);

  float4v acc[8][4];
  #pragma unroll
  for (int i = 0; i < 8; i++)
    #pragma unroll
    for (int j = 0; j < 4; j++) acc[i][j] = (float4v)(0.0f);

  // pre-zero halo rows (w=-1 -> row 0, w=128 -> row 129) of both buffers/planes
  if (tid < 32) {
    int buf = tid >> 4, pl = (tid >> 3) & 1, hr = (tid >> 2) & 1, gg = tid & 3;
    *(short8*)&A_s[buf * 8320 + pl * 4160 + hr * 4128 + gg * 8] = (short8)0;
  }

  bool nIsA = true, av0 = false, av1 = false;
  const short* bB = nullptr;
  int r0 = 0, ci0 = 0;

  auto decode = [&](int t) {
    nIsA = (t < chunksA);
    if (nIsA) {
      int dy = t / ncA, c = t % ncA;
      r0  = h0 + dy - 1;
      av0 = (r0 >= 0);
      av1 = (r0 + 1 <= HH - 1);
      ci0 = c * 32;
      bB = wbA + (size_t)(dy * ncA + c) * 24576;   // 3*256*32 shorts per chunk
    } else {
      int tb = t - chunksA;
      ci0 = tb * 32;
      bB = wbB + (size_t)tb * 8192;                // 256*32 shorts per chunk
    }
  };

  auto stageA = [&](int buf) {
    short* ldsb = A_s + buf * 8320 + plA * 4160 + 32 + ((wave & 3) << 9);
    if (nIsA) {
      bool valid = plA ? av1 : av0;
      int r = r0 + plA;
      if (valid) {
        const short* s = srcA + (((size_t)b * HH + r) * WW + wA) * CIN_A + ci0 + qA * 8;
        gload_lds16(s, ldsb);
        gload_lds16(s + (size_t)64 * CIN_A, ldsb + 2048);
      } else {
        *(short8*)&ldsb[lane * 8] = (short8)0;
        *(short8*)&ldsb[2048 + lane * 8] = (short8)0;
      }
    } else {
      const short* s = xB + (((size_t)b * HH + h0 + plA) * WW + wA) * 256 + ci0 + qA * 8;
      gload_lds16(s, ldsb);
      gload_lds16(s + (size_t)64 * 256, ldsb + 2048);
    }
  };

  auto stageB = [&](int buf) {
    short* Bb = B_s + buf * 24576;
    if (nIsA) {
      #pragma unroll
      for (int i = 0; i < 6; i++)
        gload_lds16(bB + ((size_t)i * 512 + tid) * 8, Bb + (i * 512 + wave * 64) * 8);
    } else {
      #pragma unroll
      for (int i = 0; i < 2; i++)
        gload_lds16(bB + ((size_t)i * 512 + tid) * 8, Bb + (i * 512 + wave * 64) * 8);
    }
  };

  int cur = 0;

  auto mfma_dx = [&](int adx, int bdx) {
    const short* Ab = A_s + cur * 8320 + wm * 4160;
    const short* Bb = B_s + cur * 24576;
    short8 bfv[4];
    #pragma unroll
    for (int ni = 0; ni < 4; ni++)
      bfv[ni] = *(const short8*)&Bb[swz(bdx * 256 + wn * 64 + ni * 16 + lr, lk)];
    #pragma unroll
    for (int mi = 0; mi < 8; mi++) {
      short8 afv = *(const short8*)&Ab[swz(mi * 16 + lr + adx, lk)];
      #pragma unroll
      for (int ni = 0; ni < 4; ni++)
        acc[mi][ni] = __builtin_amdgcn_mfma_f32_16x16x32_bf16(afv, bfv[ni], acc[mi][ni], 0, 0, 0);
    }
  };

  // prologue: stage chunk 0 into buf0
  decode(0);
  stageA(0);
  stageB(0);
  asm volatile("s_waitcnt vmcnt(0) lgkmcnt(0)" ::: "memory");
  __builtin_amdgcn_s_barrier();
  __builtin_amdgcn_sched_barrier(0);

  #pragma unroll 1
  for (int t = 0; t < total; t++) {
    const bool isA = (t < chunksA);
    const bool hnext = (t + 1 < total);
    if (hnext) { decode(t + 1); stageA(cur ^ 1); stageB(cur ^ 1); }
    __builtin_amdgcn_sched_barrier(0);     // pin DMA issue before MFMA phase

    __builtin_amdgcn_s_setprio(1);
    if (isA) {
      mfma_dx(0, 0);
      mfma_dx(1, 1);
      mfma_dx(2, 2);
    } else {
      mfma_dx(1, 0);                        // A stored at rows w+1; 1x1 B at rows 0..255
    }
    __builtin_amdgcn_s_setprio(0);

    asm volatile("s_waitcnt vmcnt(0) lgkmcnt(0)" ::: "memory");
    __builtin_amdgcn_s_barrier();
    __builtin_amdgcn_sched_barrier(0);
    cur ^= 1;
  }

  // ---------- epilogue: +shift (from raw BN params), relu, store ----------
  // bf16 outputs are written PRE-SWIZZLED (apat) for the next conv's linear A-DMA.
  const int h2 = h0 + wm;
  #pragma unroll
  for (int ni = 0; ni < 4; ni++) {
    int c = wn * 64 + ni * 16 + lr;           // co 0..255
    float sh;
    if (SHIFT_MODE == 0) {
      float s = g0[c] * rsqrtf(v0p[c] + 1e-5f);
      sh = b0[c] - m0[c] * s;
    } else if (SHIFT_MODE == 1) {
      int cc = c & 127;
      const float* gg = (c < 128) ? g0 : g1;
      const float* bb = (c < 128) ? b0 : b1;
      const float* mm = (c < 128) ? m0 : m1;
      const float* vv = (c < 128) ? v0p : v1p;
      float s = gg[cc] * rsqrtf(vv[cc] + 1e-5f);
      sh = bb[cc] - mm[cc] * s;
    } else {
      float s0 = g0[c] * rsqrtf(v0p[c] + 1e-5f);
      float s1 = g1[c] * rsqrtf(v1p[c] + 1e-5f);
      sh = (b0[c] - m0[c] * s0) + (b1[c] - m1[c] * s1);
    }
    #pragma unroll
    for (int mi = 0; mi < 8; mi++) {
      int w = mi * 16 + lk * 4;
      float4v v = acc[mi][ni];
      v.x = fmaxf(v.x + sh, 0.0f);
      v.y = fmaxf(v.y + sh, 0.0f);
      v.z = fmaxf(v.z + sh, 0.0f);
      v.w = fmaxf(v.w + sh, 0.0f);
      if (OUT_F32) {
        float* ob = (float*)out0;
        *(float4v*)(ob + ((size_t)b * 256 + c) * HWSZ + (size_t)h2 * WW + w) = v;
      } else if (SPLIT_OUT) {
        short* ob = (short*)((c < 128) ? out0 : out1);
        int cc = c & 127;
        size_t rowb = ((size_t)b * HH + h2) * WW + w;
        ob[(rowb    ) * 128 + (cc ^ (apat(w    ) << 3))] = f2bf(v.x);
        ob[(rowb + 1) * 128 + (cc ^ (apat(w + 1) << 3))] = f2bf(v.y);
        ob[(rowb + 2) * 128 + (cc ^ (apat(w + 2) << 3))] = f2bf(v.z);
        ob[(rowb + 3) * 128 + (cc ^ (apat(w + 3) << 3))] = f2bf(v.w);
      } else {
        short* ob = (short*)out0;
        size_t rowb = ((size_t)b * HH + h2) * WW + w;
        ob[(rowb    ) * 256 + (c ^ (apat(w    ) << 3))] = f2bf(v.x);
        ob[(rowb + 1) * 256 + (c ^ (apat(w + 1) << 3))] = f2bf(v.y);
        ob[(rowb + 2) * 256 + (c ^ (apat(w + 2) << 3))] = f2bf(v.z);
        ob[(rowb + 3) * 256 + (c ^ (apat(w + 3) << 3))] = f2bf(v.w);
      }
    }
  }
}

// ---------------- reverse cummax over H on bf16 NHWC [b][h][w][128], in place
// (channel positions are w-swizzled but constant over h -> positionwise scan is correct)
__global__ void colscan_kernel(unsigned* __restrict__ p) {  // uint = 2 bf16
  const int t = threadIdx.x;
  const int wl = t >> 6, cp = t & 63;
  const int w = blockIdx.x * 4 + wl;
  const int b = blockIdx.y;
  float m0 = -INFINITY, m1 = -INFINITY;
  for (int h = HH - 1; h >= 0; h--) {
    size_t idx = (((size_t)b * HH + h) * WW + w) * 64 + cp;
    unsigned u = p[idx];
    float f0 = bf2f((unsigned short)(u & 0xffff));
    float f1 = bf2f((unsigned short)(u >> 16));
    m0 = fmaxf(m0, f0);
    m1 = fmaxf(m1, f1);
    p[idx] = ((unsigned)(unsigned short)f2bf(m1) << 16) | (unsigned short)f2bf(m0);
  }
}

// ---------------- reverse cummax over W on p2 + add p1 -> p1 (bf16 NHWC C=128, swizzled)
__global__ __launch_bounds__(256) void rowscan_add_kernel(
    const short* __restrict__ p2, short* __restrict__ p1) {
  __shared__ short pl[128 * 128];
  const int tid = threadIdx.x;
  const int hb = blockIdx.x;
  const int b  = blockIdx.y;
  const size_t base = (((size_t)b * HH + hb) * WW) * 128;

  #pragma unroll
  for (int i = 0; i < 8; i++) {
    int idx = tid + i * 256;          // granule of 8 shorts
    *(short8*)&pl[idx * 8] = *(const short8*)(p2 + base + (size_t)idx * 8);
  }
  __syncthreads();
  if (tid < 128) {
    // scan channel `tid`; its position at column w is tid ^ (apat(w)<<3)
    float m = -INFINITY;
    for (int w = WW - 1; w >= 0; w--) {
      int a = w * 128 + (tid ^ (apat(w) << 3));
      m = fmaxf(m, bf2f((unsigned short)pl[a]));
      pl[a] = (short)f2bf(m);
    }
  }
  __syncthreads();
  #pragma unroll
  for (int i = 0; i < 8; i++) {
    int idx = tid + i * 256;
    short8 sv = *(const short8*)&pl[idx * 8];
    short8 ov = *(const short8*)(p1 + base + (size_t)idx * 8);
    short8 rv;
    #pragma unroll
    for (int j = 0; j < 8; j++)
      rv[j] = f2bf(bf2f((unsigned short)sv[j]) + bf2f((unsigned short)ov[j]));
    *(short8*)(p1 + base + (size_t)idx * 8) = rv;
  }
}

extern "C" void kernel_launch(void* const* d_in, const int* in_sizes, int n_in,
                              void* d_out, int out_size, void* d_ws, size_t ws_size,
                              hipStream_t stream) {
  const float* x    = (const float*)d_in[0];
  const float* w_p1 = (const float*)d_in[1];
  const float* g_p1 = (const float*)d_in[2];
  const float* b_p1 = (const float*)d_in[3];
  const float* m_p1 = (const float*)d_in[4];
  const float* v_p1 = (const float*)d_in[5];
  const float* w_p2 = (const float*)d_in[6];
  const float* g_p2 = (const float*)d_in[7];
  const float* b_p2 = (const float*)d_in[8];
  const float* m_p2 = (const float*)d_in[9];
  const float* v_p2 = (const float*)d_in[10];
  const float* w_c1 = (const float*)d_in[11];
  const float* g_c1 = (const float*)d_in[12];
  const float* b_c1 = (const float*)d_in[13];
  const float* m_c1 = (const float*)d_in[14];
  const float* v_c1 = (const float*)d_in[15];
  const float* w_c2 = (const float*)d_in[16];
  const float* g_c2 = (const float*)d_in[17];
  const float* b_c2 = (const float*)d_in[18];
  const float* m_c2 = (const float*)d_in[19];
  const float* v_c2 = (const float*)d_in[20];
  const float* w_p3 = (const float*)d_in[21];
  const float* g_p3 = (const float*)d_in[22];
  const float* b_p3 = (const float*)d_in[23];
  const float* m_p3 = (const float*)d_in[24];
  const float* v_p3 = (const float*)d_in[25];

  char* ws = (char*)d_ws;
  // Persistent tensors — total exactly 100,663,296 B.
  short* p1  = (short*)(ws + 0);          // bf16 NHWC [4][128][128][128]  16 MB (swizzled)
  short* p2  = (short*)(ws + 16777216);   // bf16 NHWC [4][128][128][128]  16 MB (swizzled)
  short* r   = (short*)(ws + 33554432);   // bf16 NHWC [4][128][128][256]  32 MB (swizzled)
  short* xbf = (short*)(ws + 67108864);   // bf16 NHWC [4][128][128][256]  32 MB (swizzled)
  // Weight buffers overlay dead regions (stream-ordered):
  short* wb12 = r;                        // [9][256][256]; dead before c1 writes r
  short* wbc1 = p2;                       // [9][256][128]; written after rowscan_add
  short* wbc2 = (short*)(ws + 16777216 + 589824);  // [256][256], in p2 region
  short* wbp3 = p1;                       // [9][256][256]; written after c1

  // x -> NHWC bf16 (pre-swizzled)
  xcvt_kernel<<<dim3(128, 4), 256, 0, stream>>>(x, xbf);

  // weights for p1|p2 (into r region)
  wcvt3_kernel<<<(128 * 256 * 9 + 255) / 256, 256, 0, stream>>>(w_p1, g_p1, v_p1, wb12, 256, 128, 0);
  wcvt3_kernel<<<(128 * 256 * 9 + 255) / 256, 256, 0, stream>>>(w_p2, g_p2, v_p2, wb12, 256, 128, 128);

  // p1|p2 = relu(bn(conv3x3(x)))
  conv_mfma<256, false, 1, true, false><<<dim3(256), 512, 0, stream>>>(
      xbf, nullptr, wb12, nullptr,
      g_p1, b_p1, m_p1, v_p1, g_p2, b_p2, m_p2, v_p2, (void*)p1, (void*)p2);

  // corner pooling: cp1 in-place on p1, then s = rowscan(p2) + cp1 -> p1
  colscan_kernel<<<dim3(32, 4), 256, 0, stream>>>((unsigned*)p1);
  rowscan_add_kernel<<<dim3(128, 4), 256, 0, stream>>>(p2, p1);

  // weights for c1 (3x3) and c2 (1x1) into p2 region (p2 dead now)
  wcvt3_kernel<<<(256 * 128 * 9 + 255) / 256, 256, 0, stream>>>(w_c1, g_c1, v_c1, wbc1, 128, 256, 0);
  wcvt1_kernel<<<(256 * 256 + 255) / 256, 256, 0, stream>>>(w_c2, g_c2, v_c2, wbc2, 256, 256);

  // r = relu(bn1(conv3x3(s)) + bn2(conv1x1(x)))
  conv_mfma<128, true, 2, false, false><<<dim3(256), 512, 0, stream>>>(
      p1, xbf, wbc1, wbc2,
      g_c1, b_c1, m_c1, v_c1, g_c2, b_c2, m_c2, v_c2, (void*)r, nullptr);

  // weights for p3 into p1 region (p1 dead now)
  wcvt3_kernel<<<(256 * 256 * 9 + 255) / 256, 256, 0, stream>>>(w_p3, g_p3, v_p3, wbp3, 256, 256, 0);

  // out = relu(bn(conv3x3(r)))  — fp32 NCHW float4 stores
  conv_mfma<256, false, 0, false, true><<<dim3(256), 512, 0, stream>>>(
      r, nullptr, wbp3, nullptr,
      g_p3, b_p3, m_p3, v_p3, nullptr, nullptr, nullptr, nullptr, d_out, nullptr);
}

// Round 4
// 520.894 us; speedup vs baseline: 1.3864x; 1.0558x over previous
//
#include <hip/hip_runtime.h>
#include <math.h>

#define HH 128
#define WW 128
#define HWSZ (128*128)

typedef __attribute__((ext_vector_type(8))) short short8;
typedef __attribute__((ext_vector_type(4))) float float4v;

__device__ inline short f2bf(float f) {
  unsigned x = __float_as_uint(f);
  unsigned r = (x + 0x7fffu + ((x >> 16) & 1u)) >> 16;
  return (short)r;
}
__device__ inline float bf2f(unsigned short u) {
  return __uint_as_float(((unsigned)u) << 16);
}
// XOR-swizzled short-index of 8-short granule g in LDS row `row` (row stride 32 shorts).
__device__ inline int swz(int row, int g) {
  return row * 32 + ((g ^ ((row >> 1) & 3)) << 3);
}

// ---------------- x: NCHW fp32 -> NHWC bf16 ----
__global__ __launch_bounds__(256) void xcvt_kernel(const float* __restrict__ x,
                                                   short* __restrict__ xbf) {
  __shared__ short tile[32 * 264];
  const int t = threadIdx.x;
  const int h = blockIdx.x, b = blockIdx.y;
  for (int wc = 0; wc < 4; wc++) {
    const int w0 = wc * 32;
    __syncthreads();
    #pragma unroll
    for (int coi = 0; coi < 8; coi++) {
      int ci = coi * 32 + (t >> 3);
      int wq = t & 7;
      float4v f = *(const float4v*)&x[((size_t)b * 256 + ci) * HWSZ + h * WW + w0 + wq * 4];
      tile[(wq * 4 + 0) * 264 + ci] = f2bf(f.x);
      tile[(wq * 4 + 1) * 264 + ci] = f2bf(f.y);
      tile[(wq * 4 + 2) * 264 + ci] = f2bf(f.z);
      tile[(wq * 4 + 3) * 264 + ci] = f2bf(f.w);
    }
    __syncthreads();
    #pragma unroll
    for (int pass = 0; pass < 4; pass++) {
      int wl = pass * 8 + (t >> 5);
      int ci8 = (t & 31) * 8;
      short8 v = *(const short8*)&tile[wl * 264 + ci8];
      *(short8*)&xbf[(((size_t)b * HH + h) * WW + w0 + wl) * 256 + ci8] = v;
    }
  }
}

// ---------------- weight converts (BN scale folded) ----
__global__ void wcvt3_kernel(const float* __restrict__ w, const float* __restrict__ g,
                             const float* __restrict__ v, short* __restrict__ out,
                             int Cin, int CoutW, int co_off) {
  int idx = blockIdx.x * blockDim.x + threadIdx.x;
  int total = CoutW * Cin * 9;
  if (idx >= total) return;
  int t  = idx % 9;
  int ci = (idx / 9) % Cin;
  int co = idx / (9 * Cin);
  float s = g[co] * rsqrtf(v[co] + 1e-5f);
  out[((size_t)t * 256 + co_off + co) * Cin + ci] = f2bf(w[idx] * s);
}

__global__ void wcvt1_kernel(const float* __restrict__ w, const float* __restrict__ g,
                             const float* __restrict__ v, short* __restrict__ out,
                             int Cin, int CoutW) {
  int idx = blockIdx.x * blockDim.x + threadIdx.x;
  if (idx >= CoutW * Cin) return;
  int co = idx / Cin;
  float s = g[co] * rsqrtf(v[co] + 1e-5f);
  out[idx] = f2bf(w[idx] * s);
}

// ---------------- MFMA implicit-GEMM conv3x3 (+optional fused 1x1) ----------------
// Block: 256 thr = 4 waves. Tile: M=128 px (one image row) x N=256 co (ALL couts).
// Wave tile 64 px x 128 co (acc[4][8]). Round-0 geometry/indices EXACTLY; the change
// is double-buffered LDS + ONE lgkmcnt(0)+s_barrier per 32-ci chunk, with the
// ds_write burst and next-next-chunk load issues interleaved between dx MFMA
// clusters. 2-deep pipeline: regs hold chunk t+1 while MFMA consumes chunk t.
// LDS 115 KB -> 1 block/CU; launch_bounds(256,1) removes the VGPR cap (no spill).
template<int CIN_A, bool PHASE_B, int SHIFT_MODE, bool SPLIT_OUT, bool OUT_F32>
__global__ __launch_bounds__(256, 1) void conv_mfma(
    const short* __restrict__ srcA, const short* __restrict__ xB,
    const short* __restrict__ wbA, const short* __restrict__ wbB,
    const float* __restrict__ g0, const float* __restrict__ b0,
    const float* __restrict__ m0, const float* __restrict__ v0,
    const float* __restrict__ g1, const float* __restrict__ b1,
    const float* __restrict__ m1, const float* __restrict__ v1,
    void* __restrict__ out0, void* __restrict__ out1)
{
  __shared__ short A_s[2][130 * 32];
  __shared__ short B_s[2][3 * 256 * 32];

  const int tid  = threadIdx.x;
  const int wave = tid >> 6;
  const int lane = tid & 63;
  const int wm = wave & 1;          // px half (64)
  const int wn = wave >> 1;         // co half (128)
  const int lr = lane & 15;
  const int lk = lane >> 4;

  const int h  = blockIdx.x & 127;
  const int b  = blockIdx.x >> 7;

  constexpr int ncA = CIN_A / 32;
  const int dystart = (h == 0) ? 1 : 0;
  const int dyend   = (h == HH - 1) ? 2 : 3;
  const int chunksA = (dyend - dystart) * ncA;
  const int total   = chunksA + (PHASE_B ? 8 : 0);

  float4v acc[4][8];
  #pragma unroll
  for (int i = 0; i < 4; i++)
    #pragma unroll
    for (int j = 0; j < 8; j++) acc[i][j] = (float4v)(0.0f);

  // pipeline registers (hold chunk t+1 during chunk t)
  short8 rA[3], rB[12];

  auto decode = [&](int t, const short*& ar, const short*& bb) -> bool {
    bool isA = (t < chunksA);
    if (isA) {
      int dy  = dystart + t / ncA;
      int ci0 = (t % ncA) * 32;
      ar = srcA + (((size_t)b * HH + (h + dy - 1)) * WW) * CIN_A + ci0;
      bb = wbA + ((size_t)(dy * 3) * 256) * CIN_A + ci0;
    } else {
      int ci0 = (t - chunksA) * 32;
      ar = xB + (((size_t)b * HH + h) * WW) * 256 + ci0;
      bb = wbB + ci0;
    }
    return isA;
  };

  auto loadA = [&](const short* ar, bool isA) {
    if (isA) {
      #pragma unroll
      for (int i = 0; i < 2; i++) {
        int idx = tid + i * 256;
        int w = (idx >> 2) - 1, q = idx & 3;
        rA[i] = ((unsigned)w < (unsigned)WW)
                  ? *(const short8*)(ar + (size_t)w * CIN_A + q * 8) : (short8)(0);
      }
      if (tid < 8) {
        int idx = tid + 512;
        int w = (idx >> 2) - 1, q = idx & 3;
        rA[2] = ((unsigned)w < (unsigned)WW)
                  ? *(const short8*)(ar + (size_t)w * CIN_A + q * 8) : (short8)(0);
      }
    } else {
      #pragma unroll
      for (int i = 0; i < 2; i++) {
        int idx = tid + i * 256;
        int wp = idx >> 2, q = idx & 3;
        rA[i] = *(const short8*)(ar + (size_t)wp * 256 + q * 8);
      }
    }
  };

  auto loadB1 = [&](const short* bb, bool isA) {
    if (isA) {
      #pragma unroll
      for (int i = 0; i < 6; i++) {
        int idx = tid + i * 256;
        int dx = idx >> 10, rem = idx & 1023;
        int co = rem >> 2, q = rem & 3;
        rB[i] = *(const short8*)(bb + (size_t)(dx * 256 + co) * CIN_A + q * 8);
      }
    } else {
      #pragma unroll
      for (int i = 0; i < 4; i++) {
        int idx = tid + i * 256;
        int co = idx >> 2, q = idx & 3;
        rB[i] = *(const short8*)(bb + (size_t)co * 256 + q * 8);
      }
    }
  };

  auto loadB2 = [&](const short* bb, bool isA) {
    if (isA) {
      #pragma unroll
      for (int i = 6; i < 12; i++) {
        int idx = tid + i * 256;
        int dx = idx >> 10, rem = idx & 1023;
        int co = rem >> 2, q = rem & 3;
        rB[i] = *(const short8*)(bb + (size_t)(dx * 256 + co) * CIN_A + q * 8);
      }
    }
  };

  auto storeA = [&](int buf, bool isA) {
    short* As = A_s[buf];
    if (isA) {
      #pragma unroll
      for (int i = 0; i < 2; i++) {
        int idx = tid + i * 256;
        *(short8*)&As[swz(idx >> 2, idx & 3)] = rA[i];
      }
      if (tid < 8) {
        int idx = tid + 512;
        *(short8*)&As[swz(idx >> 2, idx & 3)] = rA[2];
      }
    } else {
      #pragma unroll
      for (int i = 0; i < 2; i++) {
        int idx = tid + i * 256;
        *(short8*)&As[swz(idx >> 2, idx & 3)] = rA[i];
      }
    }
  };

  auto storeB1 = [&](int buf, bool isA) {
    short* Bs = B_s[buf];
    if (isA) {
      #pragma unroll
      for (int i = 0; i < 6; i++) {
        int idx = tid + i * 256;
        int dx = idx >> 10, rem = idx & 1023;
        *(short8*)&Bs[swz(dx * 256 + (rem >> 2), rem & 3)] = rB[i];
      }
    } else {
      #pragma unroll
      for (int i = 0; i < 4; i++) {
        int idx = tid + i * 256;
        *(short8*)&Bs[swz(idx >> 2, idx & 3)] = rB[i];
      }
    }
  };

  auto storeB2 = [&](int buf, bool isA) {
    short* Bs = B_s[buf];
    if (isA) {
      #pragma unroll
      for (int i = 6; i < 12; i++) {
        int idx = tid + i * 256;
        int dx = idx >> 10, rem = idx & 1023;
        *(short8*)&Bs[swz(dx * 256 + (rem >> 2), rem & 3)] = rB[i];
      }
    }
  };

  auto mfma_dx = [&](int buf, int dx) {
    short8 af[4];
    #pragma unroll
    for (int mi = 0; mi < 4; mi++)
      af[mi] = *(const short8*)&A_s[buf][swz(wm * 64 + mi * 16 + lr + dx, lk)];
    #pragma unroll
    for (int ni = 0; ni < 8; ni++) {
      short8 bfr = *(const short8*)&B_s[buf][swz(dx * 256 + wn * 128 + ni * 16 + lr, lk)];
      #pragma unroll
      for (int mi = 0; mi < 4; mi++)
        acc[mi][ni] = __builtin_amdgcn_mfma_f32_16x16x32_bf16(af[mi], bfr, acc[mi][ni], 0, 0, 0);
    }
  };

  // ---- prologue: chunk 0 -> buf0 (full drain once), then issue chunk 1 loads ----
  {
    const short* ar; const short* bb;
    bool ia0 = decode(0, ar, bb);
    loadA(ar, ia0); loadB1(bb, ia0); loadB2(bb, ia0);
    storeA(0, ia0); storeB1(0, ia0); storeB2(0, ia0);  // compiler-inserted vmcnt waits
    if (total > 1) {
      const short* ar1; const short* bb1;
      bool ia1 = decode(1, ar1, bb1);
      loadA(ar1, ia1); loadB1(bb1, ia1); loadB2(bb1, ia1);  // in flight across chunk 0
    }
    asm volatile("s_waitcnt lgkmcnt(0)" ::: "memory");
    __builtin_amdgcn_s_barrier();
    __builtin_amdgcn_sched_barrier(0);
  }

  int cur = 0;
  #pragma unroll 1
  for (int t = 0; t < total; t++) {
    const bool isA = (t < chunksA);
    const bool h1  = (t + 1 < total);
    const bool sA  = (t + 1 < chunksA);     // type of chunk t+1 (what regs hold)
    const bool h2  = (t + 2 < total);

    const short* ar2 = nullptr; const short* bb2 = nullptr; bool ia2 = false;
    if (h2) ia2 = decode(t + 2, ar2, bb2);

    // dx cluster 0  ∥  store regs(t+1) part A, issue loads(t+2) part A
    mfma_dx(cur, 0);
    if (h1) storeA(cur ^ 1, sA);
    if (h2) loadA(ar2, ia2);

    if (isA) mfma_dx(cur, 1);
    if (h1) storeB1(cur ^ 1, sA);
    if (h2) loadB1(bb2, ia2);

    if (isA) mfma_dx(cur, 2);
    if (h1) storeB2(cur ^ 1, sA);
    if (h2) loadB2(bb2, ia2);

    // one barrier per chunk; loads for t+2 stay in flight across it (no vmcnt drain)
    asm volatile("s_waitcnt lgkmcnt(0)" ::: "memory");
    __builtin_amdgcn_s_barrier();
    __builtin_amdgcn_sched_barrier(0);
    cur ^= 1;
  }

  // ---------- epilogue: +shift (from raw BN params), relu, store ----------
  #pragma unroll
  for (int ni = 0; ni < 8; ni++) {
    int c = wn * 128 + ni * 16 + lr;          // co 0..255
    float sh;
    if (SHIFT_MODE == 0) {
      float s = g0[c] * rsqrtf(v0[c] + 1e-5f);
      sh = b0[c] - m0[c] * s;
    } else if (SHIFT_MODE == 1) {
      int cc = c & 127;
      const float* gg = (c < 128) ? g0 : g1;
      const float* bb = (c < 128) ? b0 : b1;
      const float* mm = (c < 128) ? m0 : m1;
      const float* vv = (c < 128) ? v0 : v1;
      float s = gg[cc] * rsqrtf(vv[cc] + 1e-5f);
      sh = bb[cc] - mm[cc] * s;
    } else {
      float s0 = g0[c] * rsqrtf(v0[c] + 1e-5f);
      float s1 = g1[c] * rsqrtf(v1[c] + 1e-5f);
      sh = (b0[c] - m0[c] * s0) + (b1[c] - m1[c] * s1);
    }
    #pragma unroll
    for (int mi = 0; mi < 4; mi++) {
      int px = wm * 64 + mi * 16 + lk * 4;
      float4v v = acc[mi][ni];
      v.x = fmaxf(v.x + sh, 0.0f);
      v.y = fmaxf(v.y + sh, 0.0f);
      v.z = fmaxf(v.z + sh, 0.0f);
      v.w = fmaxf(v.w + sh, 0.0f);
      if (OUT_F32) {
        float* ob = (float*)out0;
        *(float4v*)(ob + ((size_t)b * 256 + c) * HWSZ + (size_t)h * WW + px) = v;
      } else if (SPLIT_OUT) {
        short* ob = (short*)((c < 128) ? out0 : out1);
        size_t base = (((size_t)b * HH + h) * WW + px) * 128 + (c & 127);
        ob[base      ] = f2bf(v.x);
        ob[base + 128 ] = f2bf(v.y);
        ob[base + 256 ] = f2bf(v.z);
        ob[base + 384 ] = f2bf(v.w);
      } else {
        short* ob = (short*)out0;
        size_t base = (((size_t)b * HH + h) * WW + px) * 256 + c;
        ob[base      ] = f2bf(v.x);
        ob[base + 256 ] = f2bf(v.y);
        ob[base + 512 ] = f2bf(v.z);
        ob[base + 768 ] = f2bf(v.w);
      }
    }
  }
}

// ---------------- reverse cummax over H on bf16 NHWC [b][h][w][128], in place
__global__ void colscan_kernel(unsigned* __restrict__ p) {  // uint = 2 bf16
  const int t = threadIdx.x;
  const int wl = t >> 6, cp = t & 63;
  const int w = blockIdx.x * 4 + wl;
  const int b = blockIdx.y;
  float m0 = -INFINITY, m1 = -INFINITY;
  for (int h = HH - 1; h >= 0; h--) {
    size_t idx = (((size_t)b * HH + h) * WW + w) * 64 + cp;
    unsigned u = p[idx];
    float f0 = bf2f((unsigned short)(u & 0xffff));
    float f1 = bf2f((unsigned short)(u >> 16));
    m0 = fmaxf(m0, f0);
    m1 = fmaxf(m1, f1);
    p[idx] = ((unsigned)(unsigned short)f2bf(m1) << 16) | (unsigned short)f2bf(m0);
  }
}

// ---------------- reverse cummax over W on p2 + add p1 -> p1 (bf16 NHWC C=128)
__global__ __launch_bounds__(256) void rowscan_add_kernel(
    const short* __restrict__ p2, short* __restrict__ p1) {
  __shared__ short pl[128 * 128];
  const int tid = threadIdx.x;
  const int hb = blockIdx.x;
  const int b  = blockIdx.y;
  const size_t base = (((size_t)b * HH + hb) * WW) * 128;

  #pragma unroll
  for (int i = 0; i < 8; i++) {
    int idx = tid + i * 256;          // granule of 8 shorts
    *(short8*)&pl[idx * 8] = *(const short8*)(p2 + base + (size_t)idx * 8);
  }
  __syncthreads();
  if (tid < 128) {
    float m = -INFINITY;
    for (int w = WW - 1; w >= 0; w--) {
      int a = w * 128 + tid;
      m = fmaxf(m, bf2f((unsigned short)pl[a]));
      pl[a] = (short)f2bf(m);
    }
  }
  __syncthreads();
  #pragma unroll
  for (int i = 0; i < 8; i++) {
    int idx = tid + i * 256;
    short8 sv = *(const short8*)&pl[idx * 8];
    short8 ov = *(const short8*)(p1 + base + (size_t)idx * 8);
    short8 rv;
    #pragma unroll
    for (int j = 0; j < 8; j++)
      rv[j] = f2bf(bf2f((unsigned short)sv[j]) + bf2f((unsigned short)ov[j]));
    *(short8*)(p1 + base + (size_t)idx * 8) = rv;
  }
}

extern "C" void kernel_launch(void* const* d_in, const int* in_sizes, int n_in,
                              void* d_out, int out_size, void* d_ws, size_t ws_size,
                              hipStream_t stream) {
  const float* x    = (const float*)d_in[0];
  const float* w_p1 = (const float*)d_in[1];
  const float* g_p1 = (const float*)d_in[2];
  const float* b_p1 = (const float*)d_in[3];
  const float* m_p1 = (const float*)d_in[4];
  const float* v_p1 = (const float*)d_in[5];
  const float* w_p2 = (const float*)d_in[6];
  const float* g_p2 = (const float*)d_in[7];
  const float* b_p2 = (const float*)d_in[8];
  const float* m_p2 = (const float*)d_in[9];
  const float* v_p2 = (const float*)d_in[10];
  const float* w_c1 = (const float*)d_in[11];
  const float* g_c1 = (const float*)d_in[12];
  const float* b_c1 = (const float*)d_in[13];
  const float* m_c1 = (const float*)d_in[14];
  const float* v_c1 = (const float*)d_in[15];
  const float* w_c2 = (const float*)d_in[16];
  const float* g_c2 = (const float*)d_in[17];
  const float* b_c2 = (const float*)d_in[18];
  const float* m_c2 = (const float*)d_in[19];
  const float* v_c2 = (const float*)d_in[20];
  const float* w_p3 = (const float*)d_in[21];
  const float* g_p3 = (const float*)d_in[22];
  const float* b_p3 = (const float*)d_in[23];
  const float* m_p3 = (const float*)d_in[24];
  const float* v_p3 = (const float*)d_in[25];

  char* ws = (char*)d_ws;
  // Persistent tensors — total exactly 100,663,296 B.
  short* p1  = (short*)(ws + 0);          // bf16 NHWC [4][128][128][128]  16 MB
  short* p2  = (short*)(ws + 16777216);   // bf16 NHWC [4][128][128][128]  16 MB
  short* r   = (short*)(ws + 33554432);   // bf16 NHWC [4][128][128][256]  32 MB
  short* xbf = (short*)(ws + 67108864);   // bf16 NHWC [4][128][128][256]  32 MB
  // Weight buffers overlay dead regions (stream-ordered):
  short* wb12 = r;                        // [9][256][256]; dead before c1 writes r
  short* wbc1 = p2;                       // [9][256][128]; written after rowscan_add
  short* wbc2 = (short*)(ws + 16777216 + 589824);  // [256][256], in p2 region
  short* wbp3 = p1;                       // [9][256][256]; written after c1

  // x -> NHWC bf16
  xcvt_kernel<<<dim3(128, 4), 256, 0, stream>>>(x, xbf);

  // weights for p1|p2 (into r region)
  wcvt3_kernel<<<(128 * 256 * 9 + 255) / 256, 256, 0, stream>>>(w_p1, g_p1, v_p1, wb12, 256, 128, 0);
  wcvt3_kernel<<<(128 * 256 * 9 + 255) / 256, 256, 0, stream>>>(w_p2, g_p2, v_p2, wb12, 256, 128, 128);

  // p1|p2 = relu(bn(conv3x3(x)))
  conv_mfma<256, false, 1, true, false><<<dim3(512), 256, 0, stream>>>(
      xbf, nullptr, wb12, nullptr,
      g_p1, b_p1, m_p1, v_p1, g_p2, b_p2, m_p2, v_p2, (void*)p1, (void*)p2);

  // corner pooling: cp1 in-place on p1, then s = rowscan(p2) + cp1 -> p1
  colscan_kernel<<<dim3(32, 4), 256, 0, stream>>>((unsigned*)p1);
  rowscan_add_kernel<<<dim3(128, 4), 256, 0, stream>>>(p2, p1);

  // weights for c1 (3x3) and c2 (1x1) into p2 region (p2 dead now)
  wcvt3_kernel<<<(256 * 128 * 9 + 255) / 256, 256, 0, stream>>>(w_c1, g_c1, v_c1, wbc1, 128, 256, 0);
  wcvt1_kernel<<<(256 * 256 + 255) / 256, 256, 0, stream>>>(w_c2, g_c2, v_c2, wbc2, 256, 256);

  // r = relu(bn1(conv3x3(s)) + bn2(conv1x1(x)))
  conv_mfma<128, true, 2, false, false><<<dim3(512), 256, 0, stream>>>(
      p1, xbf, wbc1, wbc2,
      g_c1, b_c1, m_c1, v_c1, g_c2, b_c2, m_c2, v_c2, (void*)r, nullptr);

  // weights for p3 into p1 region (p1 dead now)
  wcvt3_kernel<<<(256 * 256 * 9 + 255) / 256, 256, 0, stream>>>(w_p3, g_p3, v_p3, wbp3, 256, 256, 0);

  // out = relu(bn(conv3x3(r)))  — fp32 NCHW float4 stores
  conv_mfma<256, false, 0, false, true><<<dim3(512), 256, 0, stream>>>(
      r, nullptr, wbp3, nullptr,
      g_p3, b_p3, m_p3, v_p3, nullptr, nullptr, nullptr, nullptr, d_out, nullptr);
}

// Round 5
// 436.702 us; speedup vs baseline: 1.6537x; 1.1928x over previous
//
#include <hip/hip_runtime.h>
#include <math.h>

#define HH 128
#define WW 128
#define HWSZ (128*128)

typedef __attribute__((ext_vector_type(8))) short short8;
typedef __attribute__((ext_vector_type(4))) float float4v;

__device__ inline short f2bf(float f) {
  unsigned x = __float_as_uint(f);
  unsigned r = (x + 0x7fffu + ((x >> 16) & 1u)) >> 16;
  return (short)r;
}
__device__ inline float bf2f(unsigned short u) {
  return __uint_as_float(((unsigned)u) << 16);
}
// XOR-swizzled short-index of 8-short granule g in LDS row `row` (row stride 32 shorts).
__device__ inline int swz(int row, int g) {
  return row * 32 + ((g ^ ((row >> 1) & 3)) << 3);
}

// ---------------- x: NCHW fp32 -> NHWC bf16 ----
__global__ __launch_bounds__(256) void xcvt_kernel(const float* __restrict__ x,
                                                   short* __restrict__ xbf) {
  __shared__ short tile[32 * 264];
  const int t = threadIdx.x;
  const int h = blockIdx.x, b = blockIdx.y;
  for (int wc = 0; wc < 4; wc++) {
    const int w0 = wc * 32;
    __syncthreads();
    #pragma unroll
    for (int coi = 0; coi < 8; coi++) {
      int ci = coi * 32 + (t >> 3);
      int wq = t & 7;
      float4v f = *(const float4v*)&x[((size_t)b * 256 + ci) * HWSZ + h * WW + w0 + wq * 4];
      tile[(wq * 4 + 0) * 264 + ci] = f2bf(f.x);
      tile[(wq * 4 + 1) * 264 + ci] = f2bf(f.y);
      tile[(wq * 4 + 2) * 264 + ci] = f2bf(f.z);
      tile[(wq * 4 + 3) * 264 + ci] = f2bf(f.w);
    }
    __syncthreads();
    #pragma unroll
    for (int pass = 0; pass < 4; pass++) {
      int wl = pass * 8 + (t >> 5);
      int ci8 = (t & 31) * 8;
      short8 v = *(const short8*)&tile[wl * 264 + ci8];
      *(short8*)&xbf[(((size_t)b * HH + h) * WW + w0 + wl) * 256 + ci8] = v;
    }
  }
}

// ---------------- weight converts (BN scale folded) ----
__global__ void wcvt3_kernel(const float* __restrict__ w, const float* __restrict__ g,
                             const float* __restrict__ v, short* __restrict__ out,
                             int Cin, int CoutW, int co_off) {
  int idx = blockIdx.x * blockDim.x + threadIdx.x;
  int total = CoutW * Cin * 9;
  if (idx >= total) return;
  int t  = idx % 9;
  int ci = (idx / 9) % Cin;
  int co = idx / (9 * Cin);
  float s = g[co] * rsqrtf(v[co] + 1e-5f);
  out[((size_t)t * 256 + co_off + co) * Cin + ci] = f2bf(w[idx] * s);
}

__global__ void wcvt1_kernel(const float* __restrict__ w, const float* __restrict__ g,
                             const float* __restrict__ v, short* __restrict__ out,
                             int Cin, int CoutW) {
  int idx = blockIdx.x * blockDim.x + threadIdx.x;
  if (idx >= CoutW * Cin) return;
  int co = idx / Cin;
  float s = g[co] * rsqrtf(v[co] + 1e-5f);
  out[idx] = f2bf(w[idx] * s);
}

// ---------------- MFMA implicit-GEMM conv3x3 (+optional fused 1x1), SW-pipelined ----------------
// Block: 256 thr = 4 waves. Tile: M=128 px (one image row) x N=256 co (ALL couts).
// Wave tile: 64 px x 128 co (acc[4][8]). LDS 56.5 KB single-buffer -> 2 blocks/CU;
// the two resident blocks run antiphase so one block's store/barrier phase is covered
// by the other's MFMA phase (the proven round-0 structure; all restructures regressed).
template<int CIN_A, bool PHASE_B, int SHIFT_MODE, bool SPLIT_OUT, bool OUT_F32>
__global__ __launch_bounds__(256, 2) void conv_mfma(
    const short* __restrict__ srcA, const short* __restrict__ xB,
    const short* __restrict__ wbA, const short* __restrict__ wbB,
    const float* __restrict__ g0, const float* __restrict__ b0,
    const float* __restrict__ m0, const float* __restrict__ v0,
    const float* __restrict__ g1, const float* __restrict__ b1,
    const float* __restrict__ m1, const float* __restrict__ v1,
    void* __restrict__ out0, void* __restrict__ out1)
{
  __shared__ short A_s[130 * 32];
  __shared__ short B_s[3 * 256 * 32];

  const int tid  = threadIdx.x;
  const int wave = tid >> 6;
  const int lane = tid & 63;
  const int wm = wave & 1;          // px half (64)
  const int wn = wave >> 1;         // co half (128)
  const int lr = lane & 15;
  const int lk = lane >> 4;

  const int h  = blockIdx.x & 127;
  const int b  = blockIdx.x >> 7;

  constexpr int ncA = CIN_A / 32;
  const int dystart = (h == 0) ? 1 : 0;
  const int dyend   = (h == HH - 1) ? 2 : 3;
  const int chunksA = (dyend - dystart) * ncA;
  const int total   = chunksA + (PHASE_B ? 8 : 0);

  float4v acc[4][8];
  #pragma unroll
  for (int i = 0; i < 4; i++)
    #pragma unroll
    for (int j = 0; j < 8; j++) acc[i][j] = (float4v)(0.0f);

  // pipeline registers
  short8 rA[3], rB[12];
  const short* aRow = nullptr;
  const short* bBase = nullptr;
  bool curIsA = true;

  auto decode = [&](int t, const short*& ar, const short*& bb, bool& isA) {
    isA = (t < chunksA);
    if (isA) {
      int dy  = dystart + t / ncA;
      int ci0 = (t % ncA) * 32;
      ar = srcA + (((size_t)b * HH + (h + dy - 1)) * WW) * CIN_A + ci0;
      bb = wbA + ((size_t)(dy * 3) * 256) * CIN_A + ci0;
    } else {
      int ci0 = (t - chunksA) * 32;
      ar = xB + (((size_t)b * HH + h) * WW) * 256 + ci0;
      bb = wbB + ci0;
    }
  };

  auto loadRegs = [&](const short* ar, const short* bb, bool isA) {
    if (isA) {
      #pragma unroll
      for (int i = 0; i < 2; i++) {
        int idx = tid + i * 256;
        int w = (idx >> 2) - 1, q = idx & 3;
        rA[i] = ((unsigned)w < (unsigned)WW)
                  ? *(const short8*)(ar + (size_t)w * CIN_A + q * 8) : (short8)(0);
      }
      if (tid < 8) {
        int idx = tid + 512;
        int w = (idx >> 2) - 1, q = idx & 3;
        rA[2] = ((unsigned)w < (unsigned)WW)
                  ? *(const short8*)(ar + (size_t)w * CIN_A + q * 8) : (short8)(0);
      }
      // B: 3 dx x 256 co x 4 q = 3072 granules -> 12/thread
      #pragma unroll
      for (int i = 0; i < 12; i++) {
        int idx = tid + i * 256;
        int dx = idx >> 10, rem = idx & 1023;
        int co = rem >> 2, q = rem & 3;
        rB[i] = *(const short8*)(bb + (size_t)(dx * 256 + co) * CIN_A + q * 8);
      }
    } else {
      #pragma unroll
      for (int i = 0; i < 2; i++) {
        int idx = tid + i * 256;
        int wp = idx >> 2, q = idx & 3;
        rA[i] = *(const short8*)(ar + (size_t)wp * 256 + q * 8);
      }
      // B: 256 co x 4 q = 1024 granules -> 4/thread
      #pragma unroll
      for (int i = 0; i < 4; i++) {
        int idx = tid + i * 256;
        int co = idx >> 2, q = idx & 3;
        rB[i] = *(const short8*)(bb + (size_t)co * 256 + q * 8);
      }
    }
  };

  auto storeLDS = [&](bool isA) {
    if (isA) {
      #pragma unroll
      for (int i = 0; i < 2; i++) {
        int idx = tid + i * 256;
        *(short8*)&A_s[swz(idx >> 2, idx & 3)] = rA[i];
      }
      if (tid < 8) {
        int idx = tid + 512;
        *(short8*)&A_s[swz(idx >> 2, idx & 3)] = rA[2];
      }
      #pragma unroll
      for (int i = 0; i < 12; i++) {
        int idx = tid + i * 256;
        int dx = idx >> 10, rem = idx & 1023;
        *(short8*)&B_s[swz(dx * 256 + (rem >> 2), rem & 3)] = rB[i];
      }
    } else {
      #pragma unroll
      for (int i = 0; i < 2; i++) {
        int idx = tid + i * 256;
        *(short8*)&A_s[swz(idx >> 2, idx & 3)] = rA[i];
      }
      #pragma unroll
      for (int i = 0; i < 4; i++) {
        int idx = tid + i * 256;
        *(short8*)&B_s[swz(idx >> 2, idx & 3)] = rB[i];
      }
    }
  };

  // prologue
  decode(0, aRow, bBase, curIsA);
  loadRegs(aRow, bBase, curIsA);

  for (int t = 0; t < total; t++) {
    bool isA = curIsA;
    __syncthreads();            // previous MFMA done reading LDS
    storeLDS(isA);              // waits on this chunk's global loads
    __syncthreads();
    if (t + 1 < total) {        // issue next chunk's loads; overlap with MFMA below
      decode(t + 1, aRow, bBase, curIsA);
      loadRegs(aRow, bBase, curIsA);
    }
    const int ndx = isA ? 3 : 1;
    for (int dx = 0; dx < ndx; dx++) {
      short8 af[4];
      #pragma unroll
      for (int mi = 0; mi < 4; mi++)
        af[mi] = *(const short8*)&A_s[swz(wm * 64 + mi * 16 + lr + dx, lk)];
      #pragma unroll
      for (int ni = 0; ni < 8; ni++) {
        short8 bfr = *(const short8*)&B_s[swz(dx * 256 + wn * 128 + ni * 16 + lr, lk)];
        #pragma unroll
        for (int mi = 0; mi < 4; mi++)
          acc[mi][ni] = __builtin_amdgcn_mfma_f32_16x16x32_bf16(af[mi], bfr, acc[mi][ni], 0, 0, 0);
      }
    }
  }

  // ---------- epilogue: +shift (from raw BN params), relu, store ----------
  #pragma unroll
  for (int ni = 0; ni < 8; ni++) {
    int c = wn * 128 + ni * 16 + lr;          // co 0..255
    float sh;
    if (SHIFT_MODE == 0) {
      float s = g0[c] * rsqrtf(v0[c] + 1e-5f);
      sh = b0[c] - m0[c] * s;
    } else if (SHIFT_MODE == 1) {
      int cc = c & 127;
      const float* gg = (c < 128) ? g0 : g1;
      const float* bb = (c < 128) ? b0 : b1;
      const float* mm = (c < 128) ? m0 : m1;
      const float* vv = (c < 128) ? v0 : v1;
      float s = gg[cc] * rsqrtf(vv[cc] + 1e-5f);
      sh = bb[cc] - mm[cc] * s;
    } else {
      float s0 = g0[c] * rsqrtf(v0[c] + 1e-5f);
      float s1 = g1[c] * rsqrtf(v1[c] + 1e-5f);
      sh = (b0[c] - m0[c] * s0) + (b1[c] - m1[c] * s1);
    }
    #pragma unroll
    for (int mi = 0; mi < 4; mi++) {
      int px = wm * 64 + mi * 16 + lk * 4;
      float4v v = acc[mi][ni];
      v.x = fmaxf(v.x + sh, 0.0f);
      v.y = fmaxf(v.y + sh, 0.0f);
      v.z = fmaxf(v.z + sh, 0.0f);
      v.w = fmaxf(v.w + sh, 0.0f);
      if (OUT_F32) {
        float* ob = (float*)out0;
        *(float4v*)(ob + ((size_t)b * 256 + c) * HWSZ + (size_t)h * WW + px) = v;
      } else if (SPLIT_OUT) {
        short* ob = (short*)((c < 128) ? out0 : out1);
        size_t base = (((size_t)b * HH + h) * WW + px) * 128 + (c & 127);
        ob[base      ] = f2bf(v.x);
        ob[base + 128 ] = f2bf(v.y);
        ob[base + 256 ] = f2bf(v.z);
        ob[base + 384 ] = f2bf(v.w);
      } else {
        short* ob = (short*)out0;
        size_t base = (((size_t)b * HH + h) * WW + px) * 256 + c;
        ob[base      ] = f2bf(v.x);
        ob[base + 256 ] = f2bf(v.y);
        ob[base + 512 ] = f2bf(v.z);
        ob[base + 768 ] = f2bf(v.w);
      }
    }
  }
}

// ---------------- reverse cummax over H on bf16 NHWC [b][h][w][128], in place ----
// v2: lane-parallel shuffle scan. One block per (w, b): stage the [128 h][128 c]
// w-slice into a stride-129 float LDS tile (129 % 32 == 1 -> bank-conflict-free
// lane=h column reads), suffix-scan 64-lane groups via __shfl, combine halves.
// 512 blocks (all CUs busy; old version launched 128 blocks -> half the GPU idle).
__global__ __launch_bounds__(256) void colscan_kernel(short* __restrict__ p) {
  __shared__ float xf[128 * 129];
  const int tid = threadIdx.x;
  const int w = blockIdx.x;
  const int b = blockIdx.y;
  const size_t base = (size_t)b * HH * WW * 128 + (size_t)w * 128;  // + h*WW*128 + c

  #pragma unroll
  for (int i = 0; i < 8; i++) {
    int idx = tid + i * 256;          // 0..2047: h = idx>>4, granule g = idx&15
    int h = idx >> 4, g = idx & 15;
    short8 v = *(const short8*)(p + base + (size_t)h * (WW * 128) + g * 8);
    #pragma unroll
    for (int j = 0; j < 8; j++) xf[h * 129 + g * 8 + j] = bf2f((unsigned short)v[j]);
  }
  __syncthreads();

  const int lane = tid & 63, wv = tid >> 6;
  for (int rep = 0; rep < 32; rep++) {
    int c = rep * 4 + wv;
    float lo = xf[lane * 129 + c];          // h = lane
    float hi = xf[(lane + 64) * 129 + c];   // h = lane + 64
    #pragma unroll
    for (int off = 1; off < 64; off <<= 1) {
      int src = lane + off; if (src > 63) src = 63;
      float ul = __shfl(lo, src);
      float uh = __shfl(hi, src);
      lo = fmaxf(lo, ul);
      hi = fmaxf(hi, uh);
    }
    float ht = __shfl(hi, 0);               // max over h = 64..127
    lo = fmaxf(lo, ht);
    xf[lane * 129 + c] = lo;
    xf[(lane + 64) * 129 + c] = hi;
  }
  __syncthreads();

  #pragma unroll
  for (int i = 0; i < 8; i++) {
    int idx = tid + i * 256;
    int h = idx >> 4, g = idx & 15;
    short8 v;
    #pragma unroll
    for (int j = 0; j < 8; j++) v[j] = f2bf(xf[h * 129 + g * 8 + j]);
    *(short8*)(p + base + (size_t)h * (WW * 128) + g * 8) = v;
  }
}

// ---------------- reverse cummax over W on p2 + add p1 -> p1 (bf16 NHWC C=128) ----
// v2: same shuffle-scan structure over w (all 256 threads busy; old version ran a
// 128-iteration serial loop on 128 of 256 threads).
__global__ __launch_bounds__(256) void rowscan_add_kernel(
    const short* __restrict__ p2, short* __restrict__ p1) {
  __shared__ float pf[128 * 129];
  const int tid = threadIdx.x;
  const int hb = blockIdx.x;
  const int b  = blockIdx.y;
  const size_t base = (((size_t)b * HH + hb) * WW) * 128;

  #pragma unroll
  for (int i = 0; i < 8; i++) {
    int idx = tid + i * 256;          // w = idx>>4, granule g = idx&15 (linear row)
    int w = idx >> 4, g = idx & 15;
    short8 v = *(const short8*)(p2 + base + (size_t)idx * 8);
    #pragma unroll
    for (int j = 0; j < 8; j++) pf[w * 129 + g * 8 + j] = bf2f((unsigned short)v[j]);
  }
  __syncthreads();

  const int lane = tid & 63, wv = tid >> 6;
  for (int rep = 0; rep < 32; rep++) {
    int c = rep * 4 + wv;
    float lo = pf[lane * 129 + c];          // w = lane
    float hi = pf[(lane + 64) * 129 + c];   // w = lane + 64
    #pragma unroll
    for (int off = 1; off < 64; off <<= 1) {
      int src = lane + off; if (src > 63) src = 63;
      float ul = __shfl(lo, src);
      float uh = __shfl(hi, src);
      lo = fmaxf(lo, ul);
      hi = fmaxf(hi, uh);
    }
    float ht = __shfl(hi, 0);               // max over w = 64..127
    lo = fmaxf(lo, ht);
    pf[lane * 129 + c] = lo;
    pf[(lane + 64) * 129 + c] = hi;
  }
  __syncthreads();

  #pragma unroll
  for (int i = 0; i < 8; i++) {
    int idx = tid + i * 256;
    int w = idx >> 4, g = idx & 15;
    short8 ov = *(const short8*)(p1 + base + (size_t)idx * 8);
    short8 rv;
    #pragma unroll
    for (int j = 0; j < 8; j++)
      rv[j] = f2bf(pf[w * 129 + g * 8 + j] + bf2f((unsigned short)ov[j]));
    *(short8*)(p1 + base + (size_t)idx * 8) = rv;
  }
}

extern "C" void kernel_launch(void* const* d_in, const int* in_sizes, int n_in,
                              void* d_out, int out_size, void* d_ws, size_t ws_size,
                              hipStream_t stream) {
  const float* x    = (const float*)d_in[0];
  const float* w_p1 = (const float*)d_in[1];
  const float* g_p1 = (const float*)d_in[2];
  const float* b_p1 = (const float*)d_in[3];
  const float* m_p1 = (const float*)d_in[4];
  const float* v_p1 = (const float*)d_in[5];
  const float* w_p2 = (const float*)d_in[6];
  const float* g_p2 = (const float*)d_in[7];
  const float* b_p2 = (const float*)d_in[8];
  const float* m_p2 = (const float*)d_in[9];
  const float* v_p2 = (const float*)d_in[10];
  const float* w_c1 = (const float*)d_in[11];
  const float* g_c1 = (const float*)d_in[12];
  const float* b_c1 = (const float*)d_in[13];
  const float* m_c1 = (const float*)d_in[14];
  const float* v_c1 = (const float*)d_in[15];
  const float* w_c2 = (const float*)d_in[16];
  const float* g_c2 = (const float*)d_in[17];
  const float* b_c2 = (const float*)d_in[18];
  const float* m_c2 = (const float*)d_in[19];
  const float* v_c2 = (const float*)d_in[20];
  const float* w_p3 = (const float*)d_in[21];
  const float* g_p3 = (const float*)d_in[22];
  const float* b_p3 = (const float*)d_in[23];
  const float* m_p3 = (const float*)d_in[24];
  const float* v_p3 = (const float*)d_in[25];

  char* ws = (char*)d_ws;
  // Persistent tensors — total exactly 100,663,296 B.
  short* p1  = (short*)(ws + 0);          // bf16 NHWC [4][128][128][128]  16 MB
  short* p2  = (short*)(ws + 16777216);   // bf16 NHWC [4][128][128][128]  16 MB
  short* r   = (short*)(ws + 33554432);   // bf16 NHWC [4][128][128][256]  32 MB
  short* xbf = (short*)(ws + 67108864);   // bf16 NHWC [4][128][128][256]  32 MB
  // Weight buffers overlay dead regions (stream-ordered):
  short* wb12 = r;                        // [9][256][256]; dead before c1 writes r
  short* wbc1 = p2;                       // [9][256][128]; written after rowscan_add
  short* wbc2 = (short*)(ws + 16777216 + 589824);  // [256][256], in p2 region
  short* wbp3 = p1;                       // [9][256][256]; written after c1

  // x -> NHWC bf16
  xcvt_kernel<<<dim3(128, 4), 256, 0, stream>>>(x, xbf);

  // weights for p1|p2 (into r region)
  wcvt3_kernel<<<(128 * 256 * 9 + 255) / 256, 256, 0, stream>>>(w_p1, g_p1, v_p1, wb12, 256, 128, 0);
  wcvt3_kernel<<<(128 * 256 * 9 + 255) / 256, 256, 0, stream>>>(w_p2, g_p2, v_p2, wb12, 256, 128, 128);

  // p1|p2 = relu(bn(conv3x3(x)))
  conv_mfma<256, false, 1, true, false><<<dim3(512), 256, 0, stream>>>(
      xbf, nullptr, wb12, nullptr,
      g_p1, b_p1, m_p1, v_p1, g_p2, b_p2, m_p2, v_p2, (void*)p1, (void*)p2);

  // corner pooling: cp1 in-place on p1, then s = rowscan(p2) + cp1 -> p1
  colscan_kernel<<<dim3(128, 4), 256, 0, stream>>>(p1);
  rowscan_add_kernel<<<dim3(128, 4), 256, 0, stream>>>(p2, p1);

  // weights for c1 (3x3) and c2 (1x1) into p2 region (p2 dead now)
  wcvt3_kernel<<<(256 * 128 * 9 + 255) / 256, 256, 0, stream>>>(w_c1, g_c1, v_c1, wbc1, 128, 256, 0);
  wcvt1_kernel<<<(256 * 256 + 255) / 256, 256, 0, stream>>>(w_c2, g_c2, v_c2, wbc2, 256, 256);

  // r = relu(bn1(conv3x3(s)) + bn2(conv1x1(x)))
  conv_mfma<128, true, 2, false, false><<<dim3(512), 256, 0, stream>>>(
      p1, xbf, wbc1, wbc2,
      g_c1, b_c1, m_c1, v_c1, g_c2, b_c2, m_c2, v_c2, (void*)r, nullptr);

  // weights for p3 into p1 region (p1 dead now)
  wcvt3_kernel<<<(256 * 256 * 9 + 255) / 256, 256, 0, stream>>>(w_p3, g_p3, v_p3, wbp3, 256, 256, 0);

  // out = relu(bn(conv3x3(r)))  — fp32 NCHW float4 stores
  conv_mfma<256, false, 0, false, true><<<dim3(512), 256, 0, stream>>>(
      r, nullptr, wbp3, nullptr,
      g_p3, b_p3, m_p3, v_p3, nullptr, nullptr, nullptr, nullptr, d_out, nullptr);
}

// Round 6
// 416.046 us; speedup vs baseline: 1.7358x; 1.0496x over previous
//
#include <hip/hip_runtime.h>
#include <math.h>

#define HH 128
#define WW 128
#define HWSZ (128*128)

typedef __attribute__((ext_vector_type(8))) short short8;
typedef __attribute__((ext_vector_type(4))) float float4v;

__device__ inline short f2bf(float f) {
  unsigned x = __float_as_uint(f);
  unsigned r = (x + 0x7fffu + ((x >> 16) & 1u)) >> 16;
  return (short)r;
}
__device__ inline float bf2f(unsigned short u) {
  return __uint_as_float(((unsigned)u) << 16);
}
// XOR-swizzled short-index of 8-short granule g in LDS row `row` (row stride 32 shorts).
__device__ inline int swz(int row, int g) {
  return row * 32 + ((g ^ ((row >> 1) & 3)) << 3);
}

// ---------------- prep1: xcvt (blocks 0..511) + wcvt3 p1/p2 (blocks 512..2815) ----
__global__ __launch_bounds__(256) void prep1_kernel(
    const float* __restrict__ x, short* __restrict__ xbf,
    const float* __restrict__ w_p1, const float* __restrict__ g_p1, const float* __restrict__ v_p1,
    const float* __restrict__ w_p2, const float* __restrict__ g_p2, const float* __restrict__ v_p2,
    short* __restrict__ wb12) {
  __shared__ short tile[32 * 264];
  const int bid = blockIdx.x;
  const int t = threadIdx.x;
  if (bid < 512) {
    // ---- x: NCHW fp32 -> NHWC bf16 (round-0 xcvt body) ----
    const int h = bid & 127, b = bid >> 7;
    for (int wc = 0; wc < 4; wc++) {
      const int w0 = wc * 32;
      __syncthreads();
      #pragma unroll
      for (int coi = 0; coi < 8; coi++) {
        int ci = coi * 32 + (t >> 3);
        int wq = t & 7;
        float4v f = *(const float4v*)&x[((size_t)b * 256 + ci) * HWSZ + h * WW + w0 + wq * 4];
        tile[(wq * 4 + 0) * 264 + ci] = f2bf(f.x);
        tile[(wq * 4 + 1) * 264 + ci] = f2bf(f.y);
        tile[(wq * 4 + 2) * 264 + ci] = f2bf(f.z);
        tile[(wq * 4 + 3) * 264 + ci] = f2bf(f.w);
      }
      __syncthreads();
      #pragma unroll
      for (int pass = 0; pass < 4; pass++) {
        int wl = pass * 8 + (t >> 5);
        int ci8 = (t & 31) * 8;
        short8 v = *(const short8*)&tile[wl * 264 + ci8];
        *(short8*)&xbf[(((size_t)b * HH + h) * WW + w0 + wl) * 256 + ci8] = v;
      }
    }
  } else {
    // ---- weights p1|p2 (BN scale folded), 589824 elems ----
    int e = (bid - 512) * 256 + t;
    if (e >= 589824) return;
    const float* w; const float* g; const float* v; int co_off;
    if (e < 294912) { w = w_p1; g = g_p1; v = v_p1; co_off = 0; }
    else { e -= 294912; w = w_p2; g = g_p2; v = v_p2; co_off = 128; }
    int t9 = e % 9;
    int ci = (e / 9) & 255;
    int co = e / (9 * 256);
    float s = g[co] * rsqrtf(v[co] + 1e-5f);
    wb12[((size_t)t9 * 256 + co_off + co) * 256 + ci] = f2bf(w[e] * s);
  }
}

// ---------------- prep2: wcvt3 c1 + wcvt1 c2 ----
__global__ __launch_bounds__(256) void prep2_kernel(
    const float* __restrict__ w_c1, const float* __restrict__ g_c1, const float* __restrict__ v_c1,
    const float* __restrict__ w_c2, const float* __restrict__ g_c2, const float* __restrict__ v_c2,
    short* __restrict__ wbc1, short* __restrict__ wbc2) {
  int e = blockIdx.x * 256 + threadIdx.x;
  if (e < 294912) {
    int t9 = e % 9;
    int ci = (e / 9) & 127;
    int co = e / (9 * 128);
    float s = g_c1[co] * rsqrtf(v_c1[co] + 1e-5f);
    wbc1[((size_t)t9 * 256 + co) * 128 + ci] = f2bf(w_c1[e] * s);
  } else if (e < 360448) {
    int e2 = e - 294912;
    int co = e2 >> 8;
    float s = g_c2[co] * rsqrtf(v_c2[co] + 1e-5f);
    wbc2[e2] = f2bf(w_c2[e2] * s);
  }
}

// ---------------- weight convert for p3 (standalone; runs after conv2) ----
__global__ void wcvt3_kernel(const float* __restrict__ w, const float* __restrict__ g,
                             const float* __restrict__ v, short* __restrict__ out,
                             int Cin, int CoutW, int co_off) {
  int idx = blockIdx.x * blockDim.x + threadIdx.x;
  int total = CoutW * Cin * 9;
  if (idx >= total) return;
  int t  = idx % 9;
  int ci = (idx / 9) % Cin;
  int co = idx / (9 * Cin);
  float s = g[co] * rsqrtf(v[co] + 1e-5f);
  out[((size_t)t * 256 + co_off + co) * Cin + ci] = f2bf(w[idx] * s);
}

// ---------------- MFMA implicit-GEMM conv3x3 (+optional fused 1x1), SW-pipelined ----------------
// Block: 256 thr = 4 waves. Tile: M=128 px (one image row) x N=256 co (ALL couts).
// Wave tile: 64 px x 128 co (acc[4][8]). LDS 56.5 KB single-buffer -> 2 blocks/CU;
// the two resident blocks run antiphase so one block's store/barrier phase is covered
// by the other's MFMA phase (the proven round-0 structure; all restructures regressed).
// NOTE: 16x16x32 MFMA kept deliberately — with 32-short LDS rows the XOR swizzle makes
// these fragment reads conflict-free (measured 0); 32x32x16 frags would 4-way conflict.
template<int CIN_A, bool PHASE_B, int SHIFT_MODE, bool SPLIT_OUT, bool OUT_F32>
__global__ __launch_bounds__(256, 2) void conv_mfma(
    const short* __restrict__ srcA, const short* __restrict__ xB,
    const short* __restrict__ wbA, const short* __restrict__ wbB,
    const float* __restrict__ g0, const float* __restrict__ b0,
    const float* __restrict__ m0, const float* __restrict__ v0,
    const float* __restrict__ g1, const float* __restrict__ b1,
    const float* __restrict__ m1, const float* __restrict__ v1,
    void* __restrict__ out0, void* __restrict__ out1)
{
  __shared__ short A_s[130 * 32];
  __shared__ short B_s[3 * 256 * 32];

  const int tid  = threadIdx.x;
  const int wave = tid >> 6;
  const int lane = tid & 63;
  const int wm = wave & 1;          // px half (64)
  const int wn = wave >> 1;         // co half (128)
  const int lr = lane & 15;
  const int lk = lane >> 4;

  const int h  = blockIdx.x & 127;
  const int b  = blockIdx.x >> 7;

  constexpr int ncA = CIN_A / 32;
  const int dystart = (h == 0) ? 1 : 0;
  const int dyend   = (h == HH - 1) ? 2 : 3;
  const int chunksA = (dyend - dystart) * ncA;
  const int total   = chunksA + (PHASE_B ? 8 : 0);

  float4v acc[4][8];
  #pragma unroll
  for (int i = 0; i < 4; i++)
    #pragma unroll
    for (int j = 0; j < 8; j++) acc[i][j] = (float4v)(0.0f);

  // pipeline registers
  short8 rA[3], rB[12];
  const short* aRow = nullptr;
  const short* bBase = nullptr;
  bool curIsA = true;

  auto decode = [&](int t, const short*& ar, const short*& bb, bool& isA) {
    isA = (t < chunksA);
    if (isA) {
      int dy  = dystart + t / ncA;
      int ci0 = (t % ncA) * 32;
      ar = srcA + (((size_t)b * HH + (h + dy - 1)) * WW) * CIN_A + ci0;
      bb = wbA + ((size_t)(dy * 3) * 256) * CIN_A + ci0;
    } else {
      int ci0 = (t - chunksA) * 32;
      ar = xB + (((size_t)b * HH + h) * WW) * 256 + ci0;
      bb = wbB + ci0;
    }
  };

  auto loadRegs = [&](const short* ar, const short* bb, bool isA) {
    if (isA) {
      #pragma unroll
      for (int i = 0; i < 2; i++) {
        int idx = tid + i * 256;
        int w = (idx >> 2) - 1, q = idx & 3;
        rA[i] = ((unsigned)w < (unsigned)WW)
                  ? *(const short8*)(ar + (size_t)w * CIN_A + q * 8) : (short8)(0);
      }
      if (tid < 8) {
        int idx = tid + 512;
        int w = (idx >> 2) - 1, q = idx & 3;
        rA[2] = ((unsigned)w < (unsigned)WW)
                  ? *(const short8*)(ar + (size_t)w * CIN_A + q * 8) : (short8)(0);
      }
      // B: 3 dx x 256 co x 4 q = 3072 granules -> 12/thread
      #pragma unroll
      for (int i = 0; i < 12; i++) {
        int idx = tid + i * 256;
        int dx = idx >> 10, rem = idx & 1023;
        int co = rem >> 2, q = rem & 3;
        rB[i] = *(const short8*)(bb + (size_t)(dx * 256 + co) * CIN_A + q * 8);
      }
    } else {
      #pragma unroll
      for (int i = 0; i < 2; i++) {
        int idx = tid + i * 256;
        int wp = idx >> 2, q = idx & 3;
        rA[i] = *(const short8*)(ar + (size_t)wp * 256 + q * 8);
      }
      // B: 256 co x 4 q = 1024 granules -> 4/thread
      #pragma unroll
      for (int i = 0; i < 4; i++) {
        int idx = tid + i * 256;
        int co = idx >> 2, q = idx & 3;
        rB[i] = *(const short8*)(bb + (size_t)co * 256 + q * 8);
      }
    }
  };

  auto storeLDS = [&](bool isA) {
    if (isA) {
      #pragma unroll
      for (int i = 0; i < 2; i++) {
        int idx = tid + i * 256;
        *(short8*)&A_s[swz(idx >> 2, idx & 3)] = rA[i];
      }
      if (tid < 8) {
        int idx = tid + 512;
        *(short8*)&A_s[swz(idx >> 2, idx & 3)] = rA[2];
      }
      #pragma unroll
      for (int i = 0; i < 12; i++) {
        int idx = tid + i * 256;
        int dx = idx >> 10, rem = idx & 1023;
        *(short8*)&B_s[swz(dx * 256 + (rem >> 2), rem & 3)] = rB[i];
      }
    } else {
      #pragma unroll
      for (int i = 0; i < 2; i++) {
        int idx = tid + i * 256;
        *(short8*)&A_s[swz(idx >> 2, idx & 3)] = rA[i];
      }
      #pragma unroll
      for (int i = 0; i < 4; i++) {
        int idx = tid + i * 256;
        *(short8*)&B_s[swz(idx >> 2, idx & 3)] = rB[i];
      }
    }
  };

  // prologue
  decode(0, aRow, bBase, curIsA);
  loadRegs(aRow, bBase, curIsA);

  for (int t = 0; t < total; t++) {
    bool isA = curIsA;
    __syncthreads();            // previous MFMA done reading LDS
    storeLDS(isA);              // waits on this chunk's global loads
    __syncthreads();
    if (t + 1 < total) {        // issue next chunk's loads; overlap with MFMA below
      decode(t + 1, aRow, bBase, curIsA);
      loadRegs(aRow, bBase, curIsA);
    }
    const int ndx = isA ? 3 : 1;
    for (int dx = 0; dx < ndx; dx++) {
      short8 af[4];
      #pragma unroll
      for (int mi = 0; mi < 4; mi++)
        af[mi] = *(const short8*)&A_s[swz(wm * 64 + mi * 16 + lr + dx, lk)];
      #pragma unroll
      for (int ni = 0; ni < 8; ni++) {
        short8 bfr = *(const short8*)&B_s[swz(dx * 256 + wn * 128 + ni * 16 + lr, lk)];
        #pragma unroll
        for (int mi = 0; mi < 4; mi++)
          acc[mi][ni] = __builtin_amdgcn_mfma_f32_16x16x32_bf16(af[mi], bfr, acc[mi][ni], 0, 0, 0);
      }
    }
  }

  // ---------- epilogue: +shift (from raw BN params), relu, store ----------
  #pragma unroll
  for (int ni = 0; ni < 8; ni++) {
    int c = wn * 128 + ni * 16 + lr;          // co 0..255
    float sh;
    if (SHIFT_MODE == 0) {
      float s = g0[c] * rsqrtf(v0[c] + 1e-5f);
      sh = b0[c] - m0[c] * s;
    } else if (SHIFT_MODE == 1) {
      int cc = c & 127;
      const float* gg = (c < 128) ? g0 : g1;
      const float* bb = (c < 128) ? b0 : b1;
      const float* mm = (c < 128) ? m0 : m1;
      const float* vv = (c < 128) ? v0 : v1;
      float s = gg[cc] * rsqrtf(vv[cc] + 1e-5f);
      sh = bb[cc] - mm[cc] * s;
    } else {
      float s0 = g0[c] * rsqrtf(v0[c] + 1e-5f);
      float s1 = g1[c] * rsqrtf(v1[c] + 1e-5f);
      sh = (b0[c] - m0[c] * s0) + (b1[c] - m1[c] * s1);
    }
    #pragma unroll
    for (int mi = 0; mi < 4; mi++) {
      int px = wm * 64 + mi * 16 + lk * 4;
      float4v v = acc[mi][ni];
      v.x = fmaxf(v.x + sh, 0.0f);
      v.y = fmaxf(v.y + sh, 0.0f);
      v.z = fmaxf(v.z + sh, 0.0f);
      v.w = fmaxf(v.w + sh, 0.0f);
      if (OUT_F32) {
        float* ob = (float*)out0;
        *(float4v*)(ob + ((size_t)b * 256 + c) * HWSZ + (size_t)h * WW + px) = v;
      } else if (SPLIT_OUT) {
        short* ob = (short*)((c < 128) ? out0 : out1);
        size_t base = (((size_t)b * HH + h) * WW + px) * 128 + (c & 127);
        ob[base      ] = f2bf(v.x);
        ob[base + 128 ] = f2bf(v.y);
        ob[base + 256 ] = f2bf(v.z);
        ob[base + 384 ] = f2bf(v.w);
      } else {
        short* ob = (short*)out0;
        size_t base = (((size_t)b * HH + h) * WW + px) * 256 + c;
        ob[base      ] = f2bf(v.x);
        ob[base + 256 ] = f2bf(v.y);
        ob[base + 512 ] = f2bf(v.z);
        ob[base + 768 ] = f2bf(v.w);
      }
    }
  }
}

// ---------------- reverse cummax over H on bf16 NHWC [b][h][w][128], in place ----
// v3: 2-segment parallel scan. Block = (2 w-columns, b); wave-uniform seg split:
// seg1 scans h=127..64 and finalizes; seg0 scans h=63..0 into registers, then
// max-fixes with seg1's boundary max (via LDS) and writes. Half the serial depth,
// 2x the blocks of v1.
__global__ __launch_bounds__(256) void colscan_kernel(unsigned* __restrict__ p) {
  __shared__ float sm[2][2][64];
  const int t = threadIdx.x;
  const int wl = t >> 7, seg = (t >> 6) & 1, cp = t & 63;
  const int w = blockIdx.x * 2 + wl;
  const int b = blockIdx.y;
  const size_t colbase = ((size_t)b * HH * WW + w) * 64 + cp;   // + h*(WW*64)
  float m0 = -INFINITY, m1 = -INFINITY;
  unsigned r[64];
  if (seg) {
    #pragma unroll
    for (int i = 0; i < 64; i++) {
      int h = 127 - i;
      size_t idx = colbase + (size_t)h * (WW * 64);
      unsigned u = p[idx];
      m0 = fmaxf(m0, bf2f((unsigned short)(u & 0xffff)));
      m1 = fmaxf(m1, bf2f((unsigned short)(u >> 16)));
      p[idx] = ((unsigned)(unsigned short)f2bf(m1) << 16) | (unsigned short)f2bf(m0);
    }
    sm[wl][0][cp] = m0;
    sm[wl][1][cp] = m1;
  } else {
    #pragma unroll
    for (int i = 0; i < 64; i++) {
      int h = 63 - i;
      unsigned u = p[colbase + (size_t)h * (WW * 64)];
      m0 = fmaxf(m0, bf2f((unsigned short)(u & 0xffff)));
      m1 = fmaxf(m1, bf2f((unsigned short)(u >> 16)));
      r[i] = ((unsigned)(unsigned short)f2bf(m1) << 16) | (unsigned short)f2bf(m0);
    }
  }
  __syncthreads();
  if (!seg) {
    float b0 = sm[wl][0][cp], b1 = sm[wl][1][cp];
    #pragma unroll
    for (int i = 0; i < 64; i++) {
      int h = 63 - i;
      float f0 = fmaxf(bf2f((unsigned short)(r[i] & 0xffff)), b0);
      float f1 = fmaxf(bf2f((unsigned short)(r[i] >> 16)), b1);
      p[colbase + (size_t)h * (WW * 64)] =
          ((unsigned)(unsigned short)f2bf(f1) << 16) | (unsigned short)f2bf(f0);
    }
  }
}

// ---------------- reverse cummax over W on p2 + add p1 -> p1 (bf16 NHWC C=128) ----
// round-0 v1 (proven).
__global__ __launch_bounds__(256) void rowscan_add_kernel(
    const short* __restrict__ p2, short* __restrict__ p1) {
  __shared__ short pl[128 * 128];
  const int tid = threadIdx.x;
  const int hb = blockIdx.x;
  const int b  = blockIdx.y;
  const size_t base = (((size_t)b * HH + hb) * WW) * 128;

  #pragma unroll
  for (int i = 0; i < 8; i++) {
    int idx = tid + i * 256;          // granule of 8 shorts
    *(short8*)&pl[idx * 8] = *(const short8*)(p2 + base + (size_t)idx * 8);
  }
  __syncthreads();
  if (tid < 128) {
    float m = -INFINITY;
    for (int w = WW - 1; w >= 0; w--) {
      int a = w * 128 + tid;
      m = fmaxf(m, bf2f((unsigned short)pl[a]));
      pl[a] = (short)f2bf(m);
    }
  }
  __syncthreads();
  #pragma unroll
  for (int i = 0; i < 8; i++) {
    int idx = tid + i * 256;
    short8 sv = *(const short8*)&pl[idx * 8];
    short8 ov = *(const short8*)(p1 + base + (size_t)idx * 8);
    short8 rv;
    #pragma unroll
    for (int j = 0; j < 8; j++)
      rv[j] = f2bf(bf2f((unsigned short)sv[j]) + bf2f((unsigned short)ov[j]));
    *(short8*)(p1 + base + (size_t)idx * 8) = rv;
  }
}

extern "C" void kernel_launch(void* const* d_in, const int* in_sizes, int n_in,
                              void* d_out, int out_size, void* d_ws, size_t ws_size,
                              hipStream_t stream) {
  const float* x    = (const float*)d_in[0];
  const float* w_p1 = (const float*)d_in[1];
  const float* g_p1 = (const float*)d_in[2];
  const float* b_p1 = (const float*)d_in[3];
  const float* m_p1 = (const float*)d_in[4];
  const float* v_p1 = (const float*)d_in[5];
  const float* w_p2 = (const float*)d_in[6];
  const float* g_p2 = (const float*)d_in[7];
  const float* b_p2 = (const float*)d_in[8];
  const float* m_p2 = (const float*)d_in[9];
  const float* v_p2 = (const float*)d_in[10];
  const float* w_c1 = (const float*)d_in[11];
  const float* g_c1 = (const float*)d_in[12];
  const float* b_c1 = (const float*)d_in[13];
  const float* m_c1 = (const float*)d_in[14];
  const float* v_c1 = (const float*)d_in[15];
  const float* w_c2 = (const float*)d_in[16];
  const float* g_c2 = (const float*)d_in[17];
  const float* b_c2 = (const float*)d_in[18];
  const float* m_c2 = (const float*)d_in[19];
  const float* v_c2 = (const float*)d_in[20];
  const float* w_p3 = (const float*)d_in[21];
  const float* g_p3 = (const float*)d_in[22];
  const float* b_p3 = (const float*)d_in[23];
  const float* m_p3 = (const float*)d_in[24];
  const float* v_p3 = (const float*)d_in[25];

  char* ws = (char*)d_ws;
  // Persistent tensors — total exactly 100,663,296 B.
  short* p1  = (short*)(ws + 0);          // bf16 NHWC [4][128][128][128]  16 MB
  short* p2  = (short*)(ws + 16777216);   // bf16 NHWC [4][128][128][128]  16 MB
  short* r   = (short*)(ws + 33554432);   // bf16 NHWC [4][128][128][256]  32 MB
  short* xbf = (short*)(ws + 67108864);   // bf16 NHWC [4][128][128][256]  32 MB
  // Weight buffers overlay dead regions (stream-ordered):
  short* wb12 = r;                        // [9][256][256]; dead before c1 writes r
  short* wbc1 = p2;                       // [9][256][128]; written after rowscan_add
  short* wbc2 = (short*)(ws + 16777216 + 589824);  // [256][256], in p2 region
  short* wbp3 = p1;                       // [9][256][256]; written after c1

  // x -> NHWC bf16  +  weights for p1|p2 (fused)
  prep1_kernel<<<dim3(2816), 256, 0, stream>>>(x, xbf,
      w_p1, g_p1, v_p1, w_p2, g_p2, v_p2, wb12);

  // p1|p2 = relu(bn(conv3x3(x)))
  conv_mfma<256, false, 1, true, false><<<dim3(512), 256, 0, stream>>>(
      xbf, nullptr, wb12, nullptr,
      g_p1, b_p1, m_p1, v_p1, g_p2, b_p2, m_p2, v_p2, (void*)p1, (void*)p2);

  // corner pooling: cp1 in-place on p1, then s = rowscan(p2) + cp1 -> p1
  colscan_kernel<<<dim3(64, 4), 256, 0, stream>>>((unsigned*)p1);
  rowscan_add_kernel<<<dim3(128, 4), 256, 0, stream>>>(p2, p1);

  // weights for c1 (3x3) and c2 (1x1) into p2 region (p2 dead now) — fused
  prep2_kernel<<<dim3(1408), 256, 0, stream>>>(
      w_c1, g_c1, v_c1, w_c2, g_c2, v_c2, wbc1, wbc2);

  // r = relu(bn1(conv3x3(s)) + bn2(conv1x1(x)))
  conv_mfma<128, true, 2, false, false><<<dim3(512), 256, 0, stream>>>(
      p1, xbf, wbc1, wbc2,
      g_c1, b_c1, m_c1, v_c1, g_c2, b_c2, m_c2, v_c2, (void*)r, nullptr);

  // weights for p3 into p1 region (p1 dead now)
  wcvt3_kernel<<<(256 * 256 * 9 + 255) / 256, 256, 0, stream>>>(w_p3, g_p3, v_p3, wbp3, 256, 256, 0);

  // out = relu(bn(conv3x3(r)))  — fp32 NCHW float4 stores
  conv_mfma<256, false, 0, false, true><<<dim3(512), 256, 0, stream>>>(
      r, nullptr, wbp3, nullptr,
      g_p3, b_p3, m_p3, v_p3, nullptr, nullptr, nullptr, nullptr, d_out, nullptr);
}

// Round 7
// 405.713 us; speedup vs baseline: 1.7800x; 1.0255x over previous
//
#include <hip/hip_runtime.h>
#include <math.h>

#define HH 128
#define WW 128
#define HWSZ (128*128)

typedef __attribute__((ext_vector_type(8))) short short8;
typedef __attribute__((ext_vector_type(4))) float float4v;

__device__ inline short f2bf(float f) {
  unsigned x = __float_as_uint(f);
  unsigned r = (x + 0x7fffu + ((x >> 16) & 1u)) >> 16;
  return (short)r;
}
__device__ inline float bf2f(unsigned short u) {
  return __uint_as_float(((unsigned)u) << 16);
}
// XOR-swizzled short-index of 8-short granule g in LDS row `row` (row stride 32 shorts).
__device__ inline int swz(int row, int g) {
  return row * 32 + ((g ^ ((row >> 1) & 3)) << 3);
}

// ---------------- prep1: xcvt (blocks 0..511) + wcvt3 p1/p2 (blocks 512..2815) ----
__global__ __launch_bounds__(256) void prep1_kernel(
    const float* __restrict__ x, short* __restrict__ xbf,
    const float* __restrict__ w_p1, const float* __restrict__ g_p1, const float* __restrict__ v_p1,
    const float* __restrict__ w_p2, const float* __restrict__ g_p2, const float* __restrict__ v_p2,
    short* __restrict__ wb12) {
  __shared__ short tile[32 * 264];
  const int bid = blockIdx.x;
  const int t = threadIdx.x;
  if (bid < 512) {
    // ---- x: NCHW fp32 -> NHWC bf16 (round-0 xcvt body) ----
    const int h = bid & 127, b = bid >> 7;
    for (int wc = 0; wc < 4; wc++) {
      const int w0 = wc * 32;
      __syncthreads();
      #pragma unroll
      for (int coi = 0; coi < 8; coi++) {
        int ci = coi * 32 + (t >> 3);
        int wq = t & 7;
        float4v f = *(const float4v*)&x[((size_t)b * 256 + ci) * HWSZ + h * WW + w0 + wq * 4];
        tile[(wq * 4 + 0) * 264 + ci] = f2bf(f.x);
        tile[(wq * 4 + 1) * 264 + ci] = f2bf(f.y);
        tile[(wq * 4 + 2) * 264 + ci] = f2bf(f.z);
        tile[(wq * 4 + 3) * 264 + ci] = f2bf(f.w);
      }
      __syncthreads();
      #pragma unroll
      for (int pass = 0; pass < 4; pass++) {
        int wl = pass * 8 + (t >> 5);
        int ci8 = (t & 31) * 8;
        short8 v = *(const short8*)&tile[wl * 264 + ci8];
        *(short8*)&xbf[(((size_t)b * HH + h) * WW + w0 + wl) * 256 + ci8] = v;
      }
    }
  } else {
    // ---- weights p1|p2 (BN scale folded), 589824 elems ----
    int e = (bid - 512) * 256 + t;
    if (e >= 589824) return;
    const float* w; const float* g; const float* v; int co_off;
    if (e < 294912) { w = w_p1; g = g_p1; v = v_p1; co_off = 0; }
    else { e -= 294912; w = w_p2; g = g_p2; v = v_p2; co_off = 128; }
    int t9 = e % 9;
    int ci = (e / 9) & 255;
    int co = e / (9 * 256);
    float s = g[co] * rsqrtf(v[co] + 1e-5f);
    wb12[((size_t)t9 * 256 + co_off + co) * 256 + ci] = f2bf(w[e] * s);
  }
}

// ---------------- prep2: wcvt3 c1 + wcvt1 c2 + wcvt3 p3 ----
__global__ __launch_bounds__(256) void prep2_kernel(
    const float* __restrict__ w_c1, const float* __restrict__ g_c1, const float* __restrict__ v_c1,
    const float* __restrict__ w_c2, const float* __restrict__ g_c2, const float* __restrict__ v_c2,
    const float* __restrict__ w_p3, const float* __restrict__ g_p3, const float* __restrict__ v_p3,
    short* __restrict__ wbc1, short* __restrict__ wbc2, short* __restrict__ wbp3) {
  int e = blockIdx.x * 256 + threadIdx.x;
  if (e < 294912) {
    int t9 = e % 9;
    int ci = (e / 9) & 127;
    int co = e / (9 * 128);
    float s = g_c1[co] * rsqrtf(v_c1[co] + 1e-5f);
    wbc1[((size_t)t9 * 256 + co) * 128 + ci] = f2bf(w_c1[e] * s);
  } else if (e < 360448) {
    int e2 = e - 294912;
    int co = e2 >> 8;
    float s = g_c2[co] * rsqrtf(v_c2[co] + 1e-5f);
    wbc2[e2] = f2bf(w_c2[e2] * s);
  } else if (e < 950272) {
    int e3 = e - 360448;                      // 589824 elems, [256co][256ci][3][3]
    int t9 = e3 % 9;
    int ci = (e3 / 9) & 255;
    int co = e3 / (9 * 256);
    float s = g_p3[co] * rsqrtf(v_p3[co] + 1e-5f);
    wbp3[((size_t)t9 * 256 + co) * 256 + ci] = f2bf(w_p3[e3] * s);
  }
}

// ---------------- MFMA implicit-GEMM conv3x3 (+optional fused 1x1), SW-pipelined ----------------
// Block: 256 thr = 4 waves. Tile: M=128 px (one image row) x N=256 co (ALL couts).
// Wave tile: 64 px x 128 co (acc[4][8]). LDS 56.5 KB single-buffer -> 2 blocks/CU;
// the two resident blocks run antiphase so one block's store/barrier phase is covered
// by the other's MFMA phase (the proven round-0 structure; all restructures regressed).
// NOTE: 16x16x32 MFMA kept deliberately — with 32-short LDS rows the XOR swizzle makes
// these fragment reads conflict-free (measured 0); 32x32x16 frags would 4-way conflict.
template<int CIN_A, bool PHASE_B, int SHIFT_MODE, bool SPLIT_OUT, bool OUT_F32>
__global__ __launch_bounds__(256, 2) void conv_mfma(
    const short* __restrict__ srcA, const short* __restrict__ xB,
    const short* __restrict__ wbA, const short* __restrict__ wbB,
    const float* __restrict__ g0, const float* __restrict__ b0,
    const float* __restrict__ m0, const float* __restrict__ v0,
    const float* __restrict__ g1, const float* __restrict__ b1,
    const float* __restrict__ m1, const float* __restrict__ v1,
    void* __restrict__ out0, void* __restrict__ out1)
{
  __shared__ short A_s[130 * 32];
  __shared__ short B_s[3 * 256 * 32];

  const int tid  = threadIdx.x;
  const int wave = tid >> 6;
  const int lane = tid & 63;
  const int wm = wave & 1;          // px half (64)
  const int wn = wave >> 1;         // co half (128)
  const int lr = lane & 15;
  const int lk = lane >> 4;

  const int h  = blockIdx.x & 127;
  const int b  = blockIdx.x >> 7;

  constexpr int ncA = CIN_A / 32;
  const int dystart = (h == 0) ? 1 : 0;
  const int dyend   = (h == HH - 1) ? 2 : 3;
  const int chunksA = (dyend - dystart) * ncA;
  const int total   = chunksA + (PHASE_B ? 8 : 0);

  float4v acc[4][8];
  #pragma unroll
  for (int i = 0; i < 4; i++)
    #pragma unroll
    for (int j = 0; j < 8; j++) acc[i][j] = (float4v)(0.0f);

  // pipeline registers
  short8 rA[3], rB[12];
  const short* aRow = nullptr;
  const short* bBase = nullptr;
  bool curIsA = true;

  auto decode = [&](int t, const short*& ar, const short*& bb, bool& isA) {
    isA = (t < chunksA);
    if (isA) {
      int dy  = dystart + t / ncA;
      int ci0 = (t % ncA) * 32;
      ar = srcA + (((size_t)b * HH + (h + dy - 1)) * WW) * CIN_A + ci0;
      bb = wbA + ((size_t)(dy * 3) * 256) * CIN_A + ci0;
    } else {
      int ci0 = (t - chunksA) * 32;
      ar = xB + (((size_t)b * HH + h) * WW) * 256 + ci0;
      bb = wbB + ci0;
    }
  };

  auto loadRegs = [&](const short* ar, const short* bb, bool isA) {
    if (isA) {
      #pragma unroll
      for (int i = 0; i < 2; i++) {
        int idx = tid + i * 256;
        int w = (idx >> 2) - 1, q = idx & 3;
        rA[i] = ((unsigned)w < (unsigned)WW)
                  ? *(const short8*)(ar + (size_t)w * CIN_A + q * 8) : (short8)(0);
      }
      if (tid < 8) {
        int idx = tid + 512;
        int w = (idx >> 2) - 1, q = idx & 3;
        rA[2] = ((unsigned)w < (unsigned)WW)
                  ? *(const short8*)(ar + (size_t)w * CIN_A + q * 8) : (short8)(0);
      }
      // B: 3 dx x 256 co x 4 q = 3072 granules -> 12/thread
      #pragma unroll
      for (int i = 0; i < 12; i++) {
        int idx = tid + i * 256;
        int dx = idx >> 10, rem = idx & 1023;
        int co = rem >> 2, q = rem & 3;
        rB[i] = *(const short8*)(bb + (size_t)(dx * 256 + co) * CIN_A + q * 8);
      }
    } else {
      #pragma unroll
      for (int i = 0; i < 2; i++) {
        int idx = tid + i * 256;
        int wp = idx >> 2, q = idx & 3;
        rA[i] = *(const short8*)(ar + (size_t)wp * 256 + q * 8);
      }
      // B: 256 co x 4 q = 1024 granules -> 4/thread
      #pragma unroll
      for (int i = 0; i < 4; i++) {
        int idx = tid + i * 256;
        int co = idx >> 2, q = idx & 3;
        rB[i] = *(const short8*)(bb + (size_t)co * 256 + q * 8);
      }
    }
  };

  auto storeLDS = [&](bool isA) {
    if (isA) {
      #pragma unroll
      for (int i = 0; i < 2; i++) {
        int idx = tid + i * 256;
        *(short8*)&A_s[swz(idx >> 2, idx & 3)] = rA[i];
      }
      if (tid < 8) {
        int idx = tid + 512;
        *(short8*)&A_s[swz(idx >> 2, idx & 3)] = rA[2];
      }
      #pragma unroll
      for (int i = 0; i < 12; i++) {
        int idx = tid + i * 256;
        int dx = idx >> 10, rem = idx & 1023;
        *(short8*)&B_s[swz(dx * 256 + (rem >> 2), rem & 3)] = rB[i];
      }
    } else {
      #pragma unroll
      for (int i = 0; i < 2; i++) {
        int idx = tid + i * 256;
        *(short8*)&A_s[swz(idx >> 2, idx & 3)] = rA[i];
      }
      #pragma unroll
      for (int i = 0; i < 4; i++) {
        int idx = tid + i * 256;
        *(short8*)&B_s[swz(idx >> 2, idx & 3)] = rB[i];
      }
    }
  };

  // prologue
  decode(0, aRow, bBase, curIsA);
  loadRegs(aRow, bBase, curIsA);

  for (int t = 0; t < total; t++) {
    bool isA = curIsA;
    __syncthreads();            // previous MFMA done reading LDS
    storeLDS(isA);              // waits on this chunk's global loads
    __syncthreads();
    if (t + 1 < total) {        // issue next chunk's loads; overlap with MFMA below
      decode(t + 1, aRow, bBase, curIsA);
      loadRegs(aRow, bBase, curIsA);
    }
    const int ndx = isA ? 3 : 1;
    for (int dx = 0; dx < ndx; dx++) {
      short8 af[4];
      #pragma unroll
      for (int mi = 0; mi < 4; mi++)
        af[mi] = *(const short8*)&A_s[swz(wm * 64 + mi * 16 + lr + dx, lk)];
      #pragma unroll
      for (int ni = 0; ni < 8; ni++) {
        short8 bfr = *(const short8*)&B_s[swz(dx * 256 + wn * 128 + ni * 16 + lr, lk)];
        #pragma unroll
        for (int mi = 0; mi < 4; mi++)
          acc[mi][ni] = __builtin_amdgcn_mfma_f32_16x16x32_bf16(af[mi], bfr, acc[mi][ni], 0, 0, 0);
      }
    }
  }

  // ---------- epilogue: +shift (from raw BN params), relu, store ----------
  #pragma unroll
  for (int ni = 0; ni < 8; ni++) {
    int c = wn * 128 + ni * 16 + lr;          // co 0..255
    float sh;
    if (SHIFT_MODE == 0) {
      float s = g0[c] * rsqrtf(v0[c] + 1e-5f);
      sh = b0[c] - m0[c] * s;
    } else if (SHIFT_MODE == 1) {
      int cc = c & 127;
      const float* gg = (c < 128) ? g0 : g1;
      const float* bb = (c < 128) ? b0 : b1;
      const float* mm = (c < 128) ? m0 : m1;
      const float* vv = (c < 128) ? v0 : v1;
      float s = gg[cc] * rsqrtf(vv[cc] + 1e-5f);
      sh = bb[cc] - mm[cc] * s;
    } else {
      float s0 = g0[c] * rsqrtf(v0[c] + 1e-5f);
      float s1 = g1[c] * rsqrtf(v1[c] + 1e-5f);
      sh = (b0[c] - m0[c] * s0) + (b1[c] - m1[c] * s1);
    }
    #pragma unroll
    for (int mi = 0; mi < 4; mi++) {
      int px = wm * 64 + mi * 16 + lk * 4;
      float4v v = acc[mi][ni];
      v.x = fmaxf(v.x + sh, 0.0f);
      v.y = fmaxf(v.y + sh, 0.0f);
      v.z = fmaxf(v.z + sh, 0.0f);
      v.w = fmaxf(v.w + sh, 0.0f);
      if (OUT_F32) {
        float* ob = (float*)out0;
        *(float4v*)(ob + ((size_t)b * 256 + c) * HWSZ + (size_t)h * WW + px) = v;
      } else if (SPLIT_OUT) {
        short* ob = (short*)((c < 128) ? out0 : out1);
        size_t base = (((size_t)b * HH + h) * WW + px) * 128 + (c & 127);
        ob[base      ] = f2bf(v.x);
        ob[base + 128 ] = f2bf(v.y);
        ob[base + 256 ] = f2bf(v.z);
        ob[base + 384 ] = f2bf(v.w);
      } else {
        short* ob = (short*)out0;
        size_t base = (((size_t)b * HH + h) * WW + px) * 256 + c;
        ob[base      ] = f2bf(v.x);
        ob[base + 256 ] = f2bf(v.y);
        ob[base + 512 ] = f2bf(v.z);
        ob[base + 768 ] = f2bf(v.w);
      }
    }
  }
}

// ---------------- reverse cummax over H on bf16 NHWC [b][h][w][128], in place ----
// v4: 4-segment parallel scan, one block per (w, b) -> 512 blocks (2/CU).
// Thread = (seg 0..3, channel-pair cp 0..63); each scans 32 h into registers
// (serial depth 32), then adds the suffix max of later segments via LDS.
// All max arithmetic stays in the bf16-representable domain -> bit-identical.
__global__ __launch_bounds__(256) void colscan_kernel(unsigned* __restrict__ p) {
  __shared__ float sm[4][2][64];
  const int t = threadIdx.x;
  const int seg = t >> 6, cp = t & 63;
  const int w = blockIdx.x;
  const int b = blockIdx.y;
  const size_t colbase = ((size_t)b * HH * WW + w) * 64 + cp;   // + h*(WW*64)
  float m0 = -INFINITY, m1 = -INFINITY;
  unsigned r[32];
  const int htop = seg * 32 + 31;
  #pragma unroll
  for (int i = 0; i < 32; i++) {
    int h = htop - i;
    unsigned u = p[colbase + (size_t)h * (WW * 64)];
    m0 = fmaxf(m0, bf2f((unsigned short)(u & 0xffff)));
    m1 = fmaxf(m1, bf2f((unsigned short)(u >> 16)));
    r[i] = ((unsigned)(unsigned short)f2bf(m1) << 16) | (unsigned short)f2bf(m0);
  }
  sm[seg][0][cp] = m0;
  sm[seg][1][cp] = m1;
  __syncthreads();
  float s0 = -INFINITY, s1 = -INFINITY;
  #pragma unroll
  for (int s = 0; s < 3; s++) {
    if (seg + 1 + s < 4) {
      s0 = fmaxf(s0, sm[seg + 1 + s][0][cp]);
      s1 = fmaxf(s1, sm[seg + 1 + s][1][cp]);
    }
  }
  #pragma unroll
  for (int i = 0; i < 32; i++) {
    int h = htop - i;
    float f0 = fmaxf(bf2f((unsigned short)(r[i] & 0xffff)), s0);
    float f1 = fmaxf(bf2f((unsigned short)(r[i] >> 16)), s1);
    p[colbase + (size_t)h * (WW * 64)] =
        ((unsigned)(unsigned short)f2bf(f1) << 16) | (unsigned short)f2bf(f0);
  }
}

// ---------------- reverse cummax over W on p2 + add p1 -> p1 (bf16 NHWC C=128) ----
// v3: v1 staging/add passes, but the scan uses all 256 threads = 2 segs x 128 ch
// (depth 64 vs 128). Seg-0 half is fixed during the add pass with seg-1's boundary
// max (bm[c]). Exact in bf16 domain -> bit-identical to v1.
__global__ __launch_bounds__(256) void rowscan_add_kernel(
    const short* __restrict__ p2, short* __restrict__ p1) {
  __shared__ short pl[128 * 128];
  __shared__ float bm[128];
  const int tid = threadIdx.x;
  const int hb = blockIdx.x;
  const int b  = blockIdx.y;
  const size_t base = (((size_t)b * HH + hb) * WW) * 128;

  #pragma unroll
  for (int i = 0; i < 8; i++) {
    int idx = tid + i * 256;          // granule of 8 shorts
    *(short8*)&pl[idx * 8] = *(const short8*)(p2 + base + (size_t)idx * 8);
  }
  __syncthreads();
  {
    const int seg = tid >> 7;         // 0: w 0..63, 1: w 64..127
    const int c = tid & 127;
    float m = -INFINITY;
    const int wtop = seg * 64 + 63;
    for (int i = 0; i < 64; i++) {
      int a = (wtop - i) * 128 + c;
      m = fmaxf(m, bf2f((unsigned short)pl[a]));
      pl[a] = (short)f2bf(m);
    }
    if (seg) bm[c] = m;               // max over w = 64..127
  }
  __syncthreads();
  #pragma unroll
  for (int i = 0; i < 8; i++) {
    int idx = tid + i * 256;
    int w = idx >> 4;
    short8 sv = *(const short8*)&pl[idx * 8];
    short8 ov = *(const short8*)(p1 + base + (size_t)idx * 8);
    short8 rv;
    if (w < 64) {
      #pragma unroll
      for (int j = 0; j < 8; j++) {
        float f = fmaxf(bf2f((unsigned short)sv[j]), bm[(idx & 15) * 8 + j]);
        rv[j] = f2bf(f + bf2f((unsigned short)ov[j]));
      }
    } else {
      #pragma unroll
      for (int j = 0; j < 8; j++)
        rv[j] = f2bf(bf2f((unsigned short)sv[j]) + bf2f((unsigned short)ov[j]));
    }
    *(short8*)(p1 + base + (size_t)idx * 8) = rv;
  }
}

extern "C" void kernel_launch(void* const* d_in, const int* in_sizes, int n_in,
                              void* d_out, int out_size, void* d_ws, size_t ws_size,
                              hipStream_t stream) {
  const float* x    = (const float*)d_in[0];
  const float* w_p1 = (const float*)d_in[1];
  const float* g_p1 = (const float*)d_in[2];
  const float* b_p1 = (const float*)d_in[3];
  const float* m_p1 = (const float*)d_in[4];
  const float* v_p1 = (const float*)d_in[5];
  const float* w_p2 = (const float*)d_in[6];
  const float* g_p2 = (const float*)d_in[7];
  const float* b_p2 = (const float*)d_in[8];
  const float* m_p2 = (const float*)d_in[9];
  const float* v_p2 = (const float*)d_in[10];
  const float* w_c1 = (const float*)d_in[11];
  const float* g_c1 = (const float*)d_in[12];
  const float* b_c1 = (const float*)d_in[13];
  const float* m_c1 = (const float*)d_in[14];
  const float* v_c1 = (const float*)d_in[15];
  const float* w_c2 = (const float*)d_in[16];
  const float* g_c2 = (const float*)d_in[17];
  const float* b_c2 = (const float*)d_in[18];
  const float* m_c2 = (const float*)d_in[19];
  const float* v_c2 = (const float*)d_in[20];
  const float* w_p3 = (const float*)d_in[21];
  const float* g_p3 = (const float*)d_in[22];
  const float* b_p3 = (const float*)d_in[23];
  const float* m_p3 = (const float*)d_in[24];
  const float* v_p3 = (const float*)d_in[25];

  char* ws = (char*)d_ws;
  // Persistent tensors — total exactly 100,663,296 B.
  short* p1  = (short*)(ws + 0);          // bf16 NHWC [4][128][128][128]  16 MB
  short* p2  = (short*)(ws + 16777216);   // bf16 NHWC [4][128][128][128]  16 MB
  short* r   = (short*)(ws + 33554432);   // bf16 NHWC [4][128][128][256]  32 MB
  short* xbf = (short*)(ws + 67108864);   // bf16 NHWC [4][128][128][256]  32 MB
  // Weight buffers overlay dead regions (stream-ordered):
  short* wb12 = r;                        // [9][256][256]; dead before c1 writes r
  short* wbc1 = p2;                       // [9][256][128]; written after rowscan_add
  short* wbc2 = (short*)(ws + 16777216 + 589824);            // [256][256]
  short* wbp3 = (short*)(ws + 16777216 + 589824 + 131072);   // [9][256][256], also in p2

  // x -> NHWC bf16  +  weights for p1|p2 (fused)
  prep1_kernel<<<dim3(2816), 256, 0, stream>>>(x, xbf,
      w_p1, g_p1, v_p1, w_p2, g_p2, v_p2, wb12);

  // p1|p2 = relu(bn(conv3x3(x)))
  conv_mfma<256, false, 1, true, false><<<dim3(512), 256, 0, stream>>>(
      xbf, nullptr, wb12, nullptr,
      g_p1, b_p1, m_p1, v_p1, g_p2, b_p2, m_p2, v_p2, (void*)p1, (void*)p2);

  // corner pooling: cp1 in-place on p1, then s = rowscan(p2) + cp1 -> p1
  colscan_kernel<<<dim3(128, 4), 256, 0, stream>>>((unsigned*)p1);
  rowscan_add_kernel<<<dim3(128, 4), 256, 0, stream>>>(p2, p1);

  // weights for c1 (3x3), c2 (1x1), p3 (3x3) into p2 region (p2 dead now) — fused
  prep2_kernel<<<dim3(3712), 256, 0, stream>>>(
      w_c1, g_c1, v_c1, w_c2, g_c2, v_c2, w_p3, g_p3, v_p3, wbc1, wbc2, wbp3);

  // r = relu(bn1(conv3x3(s)) + bn2(conv1x1(x)))
  conv_mfma<128, true, 2, false, false><<<dim3(512), 256, 0, stream>>>(
      p1, xbf, wbc1, wbc2,
      g_c1, b_c1, m_c1, v_c1, g_c2, b_c2, m_c2, v_c2, (void*)r, nullptr);

  // out = relu(bn(conv3x3(r)))  — fp32 NCHW float4 stores
  conv_mfma<256, false, 0, false, true><<<dim3(512), 256, 0, stream>>>(
      r, nullptr, wbp3, nullptr,
      g_p3, b_p3, m_p3, v_p3, nullptr, nullptr, nullptr, nullptr, d_out, nullptr);
}